// Round 11
// baseline (184.923 us; speedup 1.0000x reference)
//
#include <hip/hip_runtime.h>

// ---------------------------------------------------------------------------
// QuantumEntanglementLayer: 4 qubits, DIM=16, BATCH=2^20.
// out[b][w] = s^T A_w s,  A_w = Re(U^H Z_w U),  s = tensor prod of RY(|0>).
// Reduced to 4 multilinear polynomials with 81 coeffs each in (1,u_w,v_w),
// u_w = cos(tanh(x_w)*pi/2), v_w = sin(tanh(x_w)*pi/2).
//
// Measured decomposition (rounds 8/10): main ~22.9us, setup ~1us (now
// LDS-parallel), launch/serialization overhead ~10us. Main's sibling
// compilations of the same body measured 240-256 VGPR (2 waves/SIMD) with
// ~100 live scalars -> latency-bound at 2.3x its ~10us overlapped floor.
// This revision: amdgpu_num_vgpr(128) on qel_main ONLY -- a direct register
// budget (not an occupancy heuristic like launch_bounds/waves_per_eu, which
// both triggered a 64-VGPR spill storm). Rest identical to the 34.8us r10.
// ---------------------------------------------------------------------------

// Coefficients: [4 wires][27 (f0,f1,f2)][4 (f3 in .x/.y/.z, .w = pad)]
__device__ float g_coef[4 * 27 * 4];

__device__ __forceinline__ float hwsin(float rad) {
  return __builtin_amdgcn_sinf(rad * 0.15915494309189535f);  // rad -> rev
}
__device__ __forceinline__ float hwcos(float rad) {
  return __builtin_amdgcn_cosf(rad * 0.15915494309189535f);
}

__global__ __launch_bounds__(256) void qel_setup(const float* __restrict__ params) {
  __shared__ float2 U2[16][17];            // circuit state [col][row], +1 pad
  __shared__ float A[4][16][16];           // A_w
  __shared__ float S1[4][3][8][8];         // after contracting qubit0 (f0)
  __shared__ float S2[4][3][3][4][4];      // + qubit1 (f1)
  __shared__ float S3[4][3][3][3][2][2];   // + qubit2 (f2)
  const int tid = threadIdx.x;

  // ---- Phase 1 (LDS-parallel): U = circuit, one element per thread -------
  {
    const int c = tid >> 4, r = tid & 15;
    U2[c][r] = make_float2((r == c) ? 1.f : 0.f, 0.f);
    __syncthreads();

    #pragma unroll
    for (int layer = 0; layer < 2; layer++) {
      #pragma unroll
      for (int i = 0; i < 3; i++) {        // CNOT(i,i+1): cm=8>>i, tm=4>>i
        const int cm = 8 >> i, tm = 4 >> i;
        const int pr = (r & cm) ? (r ^ tm) : r;
        float2 v = U2[c][pr];
        __syncthreads();
        U2[c][r] = v;
        __syncthreads();
      }
      #pragma unroll
      for (int w = 0; w < 4; w++) {        // Rot(phi,theta,omega) on wire w
        float phi   = params[layer * 12 + w * 3 + 0];
        float theta = params[layer * 12 + w * 3 + 1];
        float omega = params[layer * 12 + w * 3 + 2];
        float ct = hwcos(theta * 0.5f), st = hwsin(theta * 0.5f);
        float ap = -0.5f * (phi + omega), am = 0.5f * (phi - omega);
        float g00r =  hwcos(ap) * ct, g00i =  hwsin(ap) * ct;
        float g01r = -hwcos(am) * st, g01i = -hwsin(am) * st;
        float g10r =  hwcos(am) * st, g10i = -hwsin(am) * st;
        float g11r =  g00r,           g11i = -g00i;
        const int tm = 8 >> w;
        const int r0 = r & ~tm, r1 = r | tm;
        const bool hi = (r & tm) != 0;
        float gar = hi ? g10r : g00r, gai = hi ? g10i : g00i;
        float gbr = hi ? g11r : g01r, gbi = hi ? g11i : g01i;
        float2 o0 = U2[c][r0], o1 = U2[c][r1];
        __syncthreads();
        float nr = gar * o0.x - gai * o0.y + gbr * o1.x - gbi * o1.y;
        float ni = gar * o0.y + gai * o0.x + gbr * o1.y + gbi * o1.x;
        U2[c][r] = make_float2(nr, ni);
        __syncthreads();
      }
      {                                    // CNOT(0,3): cm=8, tm=1
        const int pr = (r & 8) ? (r ^ 1) : r;
        float2 v = U2[c][pr];
        __syncthreads();
        U2[c][r] = v;
        __syncthreads();
      }
    }
  }

  // ---- Phase 2: A_w[j][k] = sum_i z_w[i] Re(conj(U_ij) U_ik) -------------
  {
    const int j = tid >> 4, k = tid & 15;
    float s0 = 0.f, s1 = 0.f, s2 = 0.f, s3 = 0.f;
    #pragma unroll
    for (int i = 0; i < 16; i++) {
      float2 uj = U2[j][i], uk = U2[k][i];
      float p = uj.x * uk.x + uj.y * uk.y;
      s0 += (i & 8) ? -p : p;
      s1 += (i & 4) ? -p : p;
      s2 += (i & 2) ? -p : p;
      s3 += (i & 1) ? -p : p;
    }
    A[0][j][k] = s0; A[1][j][k] = s1; A[2][j][k] = s2; A[3][j][k] = s3;
  }
  __syncthreads();

  // Basis per 2x2 block: f=0: .5(x00+x11)  f=1: .5(x00-x11)  f=2: .5(x01+x10)
  {  // Phase 3a: contract qubit0 (bit3)
    const int w = tid >> 6, j = (tid >> 3) & 7, k = tid & 7;
    float x00 = A[w][j][k],     x01 = A[w][j][k + 8];
    float x10 = A[w][j + 8][k], x11 = A[w][j + 8][k + 8];
    S1[w][0][j][k] = 0.5f * (x00 + x11);
    S1[w][1][j][k] = 0.5f * (x00 - x11);
    S1[w][2][j][k] = 0.5f * (x01 + x10);
  }
  __syncthreads();
  if (tid < 192) {  // Phase 3b: + qubit1
    const int w = tid / 48, r = tid % 48;
    const int f0 = r >> 4, j = (r >> 2) & 3, k = r & 3;
    float x00 = S1[w][f0][j][k],     x01 = S1[w][f0][j][k + 4];
    float x10 = S1[w][f0][j + 4][k], x11 = S1[w][f0][j + 4][k + 4];
    S2[w][f0][0][j][k] = 0.5f * (x00 + x11);
    S2[w][f0][1][j][k] = 0.5f * (x00 - x11);
    S2[w][f0][2][j][k] = 0.5f * (x01 + x10);
  }
  __syncthreads();
  if (tid < 144) {  // Phase 3c: + qubit2
    const int w = tid / 36, r = tid % 36;
    const int f0 = r / 12, f1 = (r >> 2) % 3, j = (r >> 1) & 1, k = r & 1;
    float x00 = S2[w][f0][f1][j][k],     x01 = S2[w][f0][f1][j][k + 2];
    float x10 = S2[w][f0][f1][j + 2][k], x11 = S2[w][f0][f1][j + 2][k + 2];
    S3[w][f0][f1][0][j][k] = 0.5f * (x00 + x11);
    S3[w][f0][f1][1][j][k] = 0.5f * (x00 - x11);
    S3[w][f0][f1][2][j][k] = 0.5f * (x01 + x10);
  }
  __syncthreads();
  if (tid < 108) {  // Phase 3d: + qubit3 -> float4 per (w,f0,f1,f2)
    const int w = tid / 27, r = tid % 27;
    const int f0 = r / 9, f1 = (r / 3) % 3, f2 = r % 3;
    float y00 = S3[w][f0][f1][f2][0][0], y01 = S3[w][f0][f1][f2][0][1];
    float y10 = S3[w][f0][f1][f2][1][0], y11 = S3[w][f0][f1][f2][1][1];
    float4 o;
    o.x = 0.5f * (y00 + y11);
    o.y = 0.5f * (y00 - y11);
    o.z = 0.5f * (y01 + y10);
    o.w = 0.f;
    ((float4*)g_coef)[tid] = o;
  }
}

// ---- main kernel: round-6 body + amdgpu_num_vgpr(128) ---------------------

#define TRIGM(xv, U, V) { \
  float e_  = __builtin_amdgcn_exp2f((xv) * 2.8853900817779268f); \
  float th_ = 1.0f - 2.0f * __builtin_amdgcn_rcpf(e_ + 1.0f); \
  U = __builtin_amdgcn_cosf(th_ * 0.25f); \
  V = __builtin_amdgcn_sinf(th_ * 0.25f); }

#define SAMPLE_TRIG(K) \
  TRIGM(X##K.x, u0_##K, v0_##K) TRIGM(X##K.y, u1_##K, v1_##K) \
  TRIGM(X##K.z, u2_##K, v2_##K) TRIGM(X##K.w, u3_##K, v3_##K)

#define ACC3(K) { \
  float t_ = fmaf(c.z, v3_##K, fmaf(c.y, u3_##K, c.x)); \
  if (e3 == 0) a3_##K = t_; \
  else a3_##K = fmaf(t_, (e3 == 1) ? u2_##K : v2_##K, a3_##K); }

#define ACC2(K) { \
  if (e2 == 0) a2_##K = a3_##K; \
  else a2_##K = fmaf(a3_##K, (e2 == 1) ? u1_##K : v1_##K, a2_##K); }

#define ACC1(K) { \
  if (e1 == 0) a1_##K = a2_##K; \
  else a1_##K = fmaf(a2_##K, (e1 == 1) ? u0_##K : v0_##K, a1_##K); }

#define CONTRACT(W) { \
  float a1_0, a1_1, a1_2, a1_3; \
  _Pragma("unroll") \
  for (int e1 = 0; e1 < 3; e1++) { \
    float a2_0, a2_1, a2_2, a2_3; \
    _Pragma("unroll") \
    for (int e2 = 0; e2 < 3; e2++) { \
      float a3_0, a3_1, a3_2, a3_3; \
      _Pragma("unroll") \
      for (int e3 = 0; e3 < 3; e3++) { \
        float4 c = Cs[(W) * 27 + (e1 * 3 + e2) * 3 + e3]; \
        ACC3(0) ACC3(1) ACC3(2) ACC3(3) \
      } \
      ACC2(0) ACC2(1) ACC2(2) ACC2(3) \
    } \
    ACC1(0) ACC1(1) ACC1(2) ACC1(3) \
    __builtin_amdgcn_sched_barrier(0); \
  } \
  o##W##_0 = a1_0; o##W##_1 = a1_1; o##W##_2 = a1_2; o##W##_3 = a1_3; }

__global__ __launch_bounds__(256)
__attribute__((amdgpu_num_vgpr(128)))
void qel_main(const float4* __restrict__ x4,
              float4* __restrict__ out4,
              int quarter) {
  __shared__ float4 Cs[108];
  const int tid = threadIdx.x;
  const int gid = blockIdx.x * 256 + tid;
  const bool act = gid < quarter;
  const int g = act ? gid : 0;

  // Issue sample loads + coefficient staging load first; both latencies
  // hide under the trig block (64 transcendental ops / thread).
  float4 X0 = x4[g];
  float4 X1 = x4[g + quarter];
  float4 X2 = x4[g + 2 * quarter];
  float4 X3 = x4[g + 3 * quarter];

  float4 cstage;
  if (tid < 108) cstage = ((const float4*)g_coef)[tid];

  float u0_0, v0_0, u1_0, v1_0, u2_0, v2_0, u3_0, v3_0;
  float u0_1, v0_1, u1_1, v1_1, u2_1, v2_1, u3_1, v3_1;
  float u0_2, v0_2, u1_2, v1_2, u2_2, v2_2, u3_2, v3_2;
  float u0_3, v0_3, u1_3, v1_3, u2_3, v2_3, u3_3, v3_3;
  SAMPLE_TRIG(0) SAMPLE_TRIG(1) SAMPLE_TRIG(2) SAMPLE_TRIG(3)

  if (tid < 108) Cs[tid] = cstage;
  __syncthreads();

  float o0_0, o0_1, o0_2, o0_3;
  float o1_0, o1_1, o1_2, o1_3;
  float o2_0, o2_1, o2_2, o2_3;
  float o3_0, o3_1, o3_2, o3_3;

  CONTRACT(0) CONTRACT(1) CONTRACT(2) CONTRACT(3)

  if (act) {
    out4[gid]               = make_float4(o0_0, o1_0, o2_0, o3_0);
    out4[gid + quarter]     = make_float4(o0_1, o1_1, o2_1, o3_1);
    out4[gid + 2 * quarter] = make_float4(o0_2, o1_2, o2_2, o3_2);
    out4[gid + 3 * quarter] = make_float4(o0_3, o1_3, o2_3, o3_3);
  }
}

// ---------------------------------------------------------------------------

extern "C" void kernel_launch(void* const* d_in, const int* in_sizes, int n_in,
                              void* d_out, int out_size, void* d_ws, size_t ws_size,
                              hipStream_t stream) {
  const float* x      = (const float*)d_in[0];   // [B,4] f32
  const float* params = (const float*)d_in[1];   // [2,4,3] f32
  float* out = (float*)d_out;                    // [B,4] f32

  int B = in_sizes[0] / 4;
  int quarter = B / 4;
  int blocks = (quarter + 255) / 256;

  qel_setup<<<1, 256, 0, stream>>>(params);
  qel_main<<<blocks, 256, 0, stream>>>((const float4*)x, (float4*)out, quarter);
}

// Round 12
// 39.525 us; speedup vs baseline: 4.6786x; 4.6786x over previous
//
#include <hip/hip_runtime.h>

// ---------------------------------------------------------------------------
// QuantumEntanglementLayer: 4 qubits, DIM=16, BATCH=2^20.
// out[b][w] = s^T A_w s,  A_w = Re(U^H Z_w U),  s = tensor prod of RY(|0>).
// Reduced to 4 multilinear polynomials with 81 coeffs each in (1,u_w,v_w),
// u_w = cos(tanh(x_w)*pi/2), v_w = sin(tanh(x_w)*pi/2).
//
// Register-pressure history: allocator balloons this body to 240-256 VGPR
// (2 waves/SIMD, latency-bound 22.9us); EVERY cap (launch_bounds, waves_per_eu,
// amdgpu_num_vgpr(128) -- honored, VGPR_Count=128) spills ~0.5-1.4 GB.
// This revision removes the pressure structurally: coefficients live in the
// d_ws workspace and reach qel_main as a const __restrict__ kernel-arg
// pointer with compile-time-constant offsets -> backend promotes the 108
// float4 loads to s_load into SGPRs (scalar cache, zero VGPR, no LDS).
// Kills both the VGPR balloon and the per-thread ds_read_b128 stream.
// ---------------------------------------------------------------------------

__device__ __forceinline__ float hwsin(float rad) {
  return __builtin_amdgcn_sinf(rad * 0.15915494309189535f);  // rad -> rev
}
__device__ __forceinline__ float hwcos(float rad) {
  return __builtin_amdgcn_cosf(rad * 0.15915494309189535f);
}

__global__ __launch_bounds__(256) void qel_setup(const float* __restrict__ params,
                                                 float4* __restrict__ coef_out) {
  __shared__ float2 U2[16][17];            // circuit state [col][row], +1 pad
  __shared__ float A[4][16][16];           // A_w
  __shared__ float S1[4][3][8][8];         // after contracting qubit0 (f0)
  __shared__ float S2[4][3][3][4][4];      // + qubit1 (f1)
  __shared__ float S3[4][3][3][3][2][2];   // + qubit2 (f2)
  const int tid = threadIdx.x;

  // ---- Phase 1 (LDS-parallel): U = circuit, one element per thread -------
  {
    const int c = tid >> 4, r = tid & 15;
    U2[c][r] = make_float2((r == c) ? 1.f : 0.f, 0.f);
    __syncthreads();

    #pragma unroll
    for (int layer = 0; layer < 2; layer++) {
      #pragma unroll
      for (int i = 0; i < 3; i++) {        // CNOT(i,i+1): cm=8>>i, tm=4>>i
        const int cm = 8 >> i, tm = 4 >> i;
        const int pr = (r & cm) ? (r ^ tm) : r;
        float2 v = U2[c][pr];
        __syncthreads();
        U2[c][r] = v;
        __syncthreads();
      }
      #pragma unroll
      for (int w = 0; w < 4; w++) {        // Rot(phi,theta,omega) on wire w
        float phi   = params[layer * 12 + w * 3 + 0];
        float theta = params[layer * 12 + w * 3 + 1];
        float omega = params[layer * 12 + w * 3 + 2];
        float ct = hwcos(theta * 0.5f), st = hwsin(theta * 0.5f);
        float ap = -0.5f * (phi + omega), am = 0.5f * (phi - omega);
        float g00r =  hwcos(ap) * ct, g00i =  hwsin(ap) * ct;
        float g01r = -hwcos(am) * st, g01i = -hwsin(am) * st;
        float g10r =  hwcos(am) * st, g10i = -hwsin(am) * st;
        float g11r =  g00r,           g11i = -g00i;
        const int tm = 8 >> w;
        const int r0 = r & ~tm, r1 = r | tm;
        const bool hi = (r & tm) != 0;
        float gar = hi ? g10r : g00r, gai = hi ? g10i : g00i;
        float gbr = hi ? g11r : g01r, gbi = hi ? g11i : g01i;
        float2 o0 = U2[c][r0], o1 = U2[c][r1];
        __syncthreads();
        float nr = gar * o0.x - gai * o0.y + gbr * o1.x - gbi * o1.y;
        float ni = gar * o0.y + gai * o0.x + gbr * o1.y + gbi * o1.x;
        U2[c][r] = make_float2(nr, ni);
        __syncthreads();
      }
      {                                    // CNOT(0,3): cm=8, tm=1
        const int pr = (r & 8) ? (r ^ 1) : r;
        float2 v = U2[c][pr];
        __syncthreads();
        U2[c][r] = v;
        __syncthreads();
      }
    }
  }

  // ---- Phase 2: A_w[j][k] = sum_i z_w[i] Re(conj(U_ij) U_ik) -------------
  {
    const int j = tid >> 4, k = tid & 15;
    float s0 = 0.f, s1 = 0.f, s2 = 0.f, s3 = 0.f;
    #pragma unroll
    for (int i = 0; i < 16; i++) {
      float2 uj = U2[j][i], uk = U2[k][i];
      float p = uj.x * uk.x + uj.y * uk.y;
      s0 += (i & 8) ? -p : p;
      s1 += (i & 4) ? -p : p;
      s2 += (i & 2) ? -p : p;
      s3 += (i & 1) ? -p : p;
    }
    A[0][j][k] = s0; A[1][j][k] = s1; A[2][j][k] = s2; A[3][j][k] = s3;
  }
  __syncthreads();

  // Basis per 2x2 block: f=0: .5(x00+x11)  f=1: .5(x00-x11)  f=2: .5(x01+x10)
  {  // Phase 3a: contract qubit0 (bit3)
    const int w = tid >> 6, j = (tid >> 3) & 7, k = tid & 7;
    float x00 = A[w][j][k],     x01 = A[w][j][k + 8];
    float x10 = A[w][j + 8][k], x11 = A[w][j + 8][k + 8];
    S1[w][0][j][k] = 0.5f * (x00 + x11);
    S1[w][1][j][k] = 0.5f * (x00 - x11);
    S1[w][2][j][k] = 0.5f * (x01 + x10);
  }
  __syncthreads();
  if (tid < 192) {  // Phase 3b: + qubit1
    const int w = tid / 48, r = tid % 48;
    const int f0 = r >> 4, j = (r >> 2) & 3, k = r & 3;
    float x00 = S1[w][f0][j][k],     x01 = S1[w][f0][j][k + 4];
    float x10 = S1[w][f0][j + 4][k], x11 = S1[w][f0][j + 4][k + 4];
    S2[w][f0][0][j][k] = 0.5f * (x00 + x11);
    S2[w][f0][1][j][k] = 0.5f * (x00 - x11);
    S2[w][f0][2][j][k] = 0.5f * (x01 + x10);
  }
  __syncthreads();
  if (tid < 144) {  // Phase 3c: + qubit2
    const int w = tid / 36, r = tid % 36;
    const int f0 = r / 12, f1 = (r >> 2) % 3, j = (r >> 1) & 1, k = r & 1;
    float x00 = S2[w][f0][f1][j][k],     x01 = S2[w][f0][f1][j][k + 2];
    float x10 = S2[w][f0][f1][j + 2][k], x11 = S2[w][f0][f1][j + 2][k + 2];
    S3[w][f0][f1][0][j][k] = 0.5f * (x00 + x11);
    S3[w][f0][f1][1][j][k] = 0.5f * (x00 - x11);
    S3[w][f0][f1][2][j][k] = 0.5f * (x01 + x10);
  }
  __syncthreads();
  if (tid < 108) {  // Phase 3d: + qubit3 -> float4 per (w,f0,f1,f2)
    const int w = tid / 27, r = tid % 27;
    const int f0 = r / 9, f1 = (r / 3) % 3, f2 = r % 3;
    float y00 = S3[w][f0][f1][f2][0][0], y01 = S3[w][f0][f1][f2][0][1];
    float y10 = S3[w][f0][f1][f2][1][0], y11 = S3[w][f0][f1][f2][1][1];
    float4 o;
    o.x = 0.5f * (y00 + y11);
    o.y = 0.5f * (y00 - y11);
    o.z = 0.5f * (y01 + y10);
    o.w = 0.f;
    coef_out[tid] = o;
  }
}

// ---- main kernel: coefficients via const __restrict__ arg -> s_load -------

#define TRIGM(xv, U, V) { \
  float e_  = __builtin_amdgcn_exp2f((xv) * 2.8853900817779268f); \
  float th_ = 1.0f - 2.0f * __builtin_amdgcn_rcpf(e_ + 1.0f); \
  U = __builtin_amdgcn_cosf(th_ * 0.25f); \
  V = __builtin_amdgcn_sinf(th_ * 0.25f); }

#define SAMPLE_TRIG(K) \
  TRIGM(X##K.x, u0_##K, v0_##K) TRIGM(X##K.y, u1_##K, v1_##K) \
  TRIGM(X##K.z, u2_##K, v2_##K) TRIGM(X##K.w, u3_##K, v3_##K)

#define ACC3(K) { \
  float t_ = fmaf(c.z, v3_##K, fmaf(c.y, u3_##K, c.x)); \
  if (e3 == 0) a3_##K = t_; \
  else a3_##K = fmaf(t_, (e3 == 1) ? u2_##K : v2_##K, a3_##K); }

#define ACC2(K) { \
  if (e2 == 0) a2_##K = a3_##K; \
  else a2_##K = fmaf(a3_##K, (e2 == 1) ? u1_##K : v1_##K, a2_##K); }

#define ACC1(K) { \
  if (e1 == 0) a1_##K = a2_##K; \
  else a1_##K = fmaf(a2_##K, (e1 == 1) ? u0_##K : v0_##K, a1_##K); }

#define CONTRACT(W) { \
  float a1_0, a1_1, a1_2, a1_3; \
  _Pragma("unroll") \
  for (int e1 = 0; e1 < 3; e1++) { \
    float a2_0, a2_1, a2_2, a2_3; \
    _Pragma("unroll") \
    for (int e2 = 0; e2 < 3; e2++) { \
      float a3_0, a3_1, a3_2, a3_3; \
      _Pragma("unroll") \
      for (int e3 = 0; e3 < 3; e3++) { \
        float4 c = coef[(W) * 27 + (e1 * 3 + e2) * 3 + e3]; \
        ACC3(0) ACC3(1) ACC3(2) ACC3(3) \
      } \
      ACC2(0) ACC2(1) ACC2(2) ACC2(3) \
    } \
    ACC1(0) ACC1(1) ACC1(2) ACC1(3) \
    __builtin_amdgcn_sched_barrier(0); \
  } \
  o##W##_0 = a1_0; o##W##_1 = a1_1; o##W##_2 = a1_2; o##W##_3 = a1_3; }

__global__ __launch_bounds__(256) void qel_main(const float4* __restrict__ x4,
                                                float4* __restrict__ out4,
                                                const float4* __restrict__ coef,
                                                int quarter) {
  const int tid = threadIdx.x;
  const int gid = blockIdx.x * 256 + tid;
  const bool act = gid < quarter;
  const int g = act ? gid : 0;

  // Sample loads issued first; HBM latency hides under the trig block.
  float4 X0 = x4[g];
  float4 X1 = x4[g + quarter];
  float4 X2 = x4[g + 2 * quarter];
  float4 X3 = x4[g + 3 * quarter];

  float u0_0, v0_0, u1_0, v1_0, u2_0, v2_0, u3_0, v3_0;
  float u0_1, v0_1, u1_1, v1_1, u2_1, v2_1, u3_1, v3_1;
  float u0_2, v0_2, u1_2, v1_2, u2_2, v2_2, u3_2, v3_2;
  float u0_3, v0_3, u1_3, v1_3, u2_3, v2_3, u3_3, v3_3;
  SAMPLE_TRIG(0) SAMPLE_TRIG(1) SAMPLE_TRIG(2) SAMPLE_TRIG(3)

  float o0_0, o0_1, o0_2, o0_3;
  float o1_0, o1_1, o1_2, o1_3;
  float o2_0, o2_1, o2_2, o2_3;
  float o3_0, o3_1, o3_2, o3_3;

  CONTRACT(0) CONTRACT(1) CONTRACT(2) CONTRACT(3)

  if (act) {
    out4[gid]               = make_float4(o0_0, o1_0, o2_0, o3_0);
    out4[gid + quarter]     = make_float4(o0_1, o1_1, o2_1, o3_1);
    out4[gid + 2 * quarter] = make_float4(o0_2, o1_2, o2_2, o3_2);
    out4[gid + 3 * quarter] = make_float4(o0_3, o1_3, o2_3, o3_3);
  }
}

// ---------------------------------------------------------------------------

extern "C" void kernel_launch(void* const* d_in, const int* in_sizes, int n_in,
                              void* d_out, int out_size, void* d_ws, size_t ws_size,
                              hipStream_t stream) {
  const float* x      = (const float*)d_in[0];   // [B,4] f32
  const float* params = (const float*)d_in[1];   // [2,4,3] f32
  float* out = (float*)d_out;                    // [B,4] f32
  float4* coef = (float4*)d_ws;                  // 108 float4 in workspace

  int B = in_sizes[0] / 4;
  int quarter = B / 4;
  int blocks = (quarter + 255) / 256;

  qel_setup<<<1, 256, 0, stream>>>(params, coef);
  qel_main<<<blocks, 256, 0, stream>>>((const float4*)x, (float4*)out,
                                       (const float4*)coef, quarter);
}

// Round 13
// 37.489 us; speedup vs baseline: 4.9327x; 1.0543x over previous
//
#include <hip/hip_runtime.h>

// ---------------------------------------------------------------------------
// QuantumEntanglementLayer: 4 qubits, DIM=16, BATCH=2^20.
// out[b][w] = s^T A_w s,  A_w = Re(U^H Z_w U),  s = tensor prod of RY(|0>).
// Reduced to 4 multilinear polynomials with 81 coeffs each in (1,u_w,v_w),
// u_w = cos(tanh(x_w)*pi/2), v_w = sin(tanh(x_w)*pi/2).
//
// Coefficient-path history (main kernel):
//   per-lane global loads ............ 39.0us   (r0)
//   LDS broadcast staging ............ 34.8us   (r10, best)
//   const __restrict__ kernel arg .... 39.5us   (r12 -- compiler did NOT
//                                               promote to s_load)
// VGPR history: body balloons to 240-256 (2 waves/SIMD); every cap attribute
// spills 0.5-1.4 GB. This revision FORCES the scalar path: inline-asm
// s_load_dwordx4 pulls each (W,e1) block's 9 coefficients into SGPR quads
// (wave-uniform data belongs in SGPRs). Main kernel has NO LDS, no vector
// coefficient loads left to hoist -> natural VGPR ~80 -> 4 waves/SIMD.
// ---------------------------------------------------------------------------

typedef __attribute__((ext_vector_type(4))) float f4s;

__device__ __forceinline__ float hwsin(float rad) {
  return __builtin_amdgcn_sinf(rad * 0.15915494309189535f);  // rad -> rev
}
__device__ __forceinline__ float hwcos(float rad) {
  return __builtin_amdgcn_cosf(rad * 0.15915494309189535f);
}

__global__ __launch_bounds__(256) void qel_setup(const float* __restrict__ params,
                                                 float4* __restrict__ coef_out) {
  __shared__ float2 U2[16][17];            // circuit state [col][row], +1 pad
  __shared__ float A[4][16][16];           // A_w
  __shared__ float S1[4][3][8][8];         // after contracting qubit0 (f0)
  __shared__ float S2[4][3][3][4][4];      // + qubit1 (f1)
  __shared__ float S3[4][3][3][3][2][2];   // + qubit2 (f2)
  const int tid = threadIdx.x;

  // ---- Phase 1 (LDS-parallel): U = circuit, one element per thread -------
  {
    const int c = tid >> 4, r = tid & 15;
    U2[c][r] = make_float2((r == c) ? 1.f : 0.f, 0.f);
    __syncthreads();

    #pragma unroll
    for (int layer = 0; layer < 2; layer++) {
      #pragma unroll
      for (int i = 0; i < 3; i++) {        // CNOT(i,i+1): cm=8>>i, tm=4>>i
        const int cm = 8 >> i, tm = 4 >> i;
        const int pr = (r & cm) ? (r ^ tm) : r;
        float2 v = U2[c][pr];
        __syncthreads();
        U2[c][r] = v;
        __syncthreads();
      }
      #pragma unroll
      for (int w = 0; w < 4; w++) {        // Rot(phi,theta,omega) on wire w
        float phi   = params[layer * 12 + w * 3 + 0];
        float theta = params[layer * 12 + w * 3 + 1];
        float omega = params[layer * 12 + w * 3 + 2];
        float ct = hwcos(theta * 0.5f), st = hwsin(theta * 0.5f);
        float ap = -0.5f * (phi + omega), am = 0.5f * (phi - omega);
        float g00r =  hwcos(ap) * ct, g00i =  hwsin(ap) * ct;
        float g01r = -hwcos(am) * st, g01i = -hwsin(am) * st;
        float g10r =  hwcos(am) * st, g10i = -hwsin(am) * st;
        float g11r =  g00r,           g11i = -g00i;
        const int tm = 8 >> w;
        const int r0 = r & ~tm, r1 = r | tm;
        const bool hi = (r & tm) != 0;
        float gar = hi ? g10r : g00r, gai = hi ? g10i : g00i;
        float gbr = hi ? g11r : g01r, gbi = hi ? g11i : g01i;
        float2 o0 = U2[c][r0], o1 = U2[c][r1];
        __syncthreads();
        float nr = gar * o0.x - gai * o0.y + gbr * o1.x - gbi * o1.y;
        float ni = gar * o0.y + gai * o0.x + gbr * o1.y + gbi * o1.x;
        U2[c][r] = make_float2(nr, ni);
        __syncthreads();
      }
      {                                    // CNOT(0,3): cm=8, tm=1
        const int pr = (r & 8) ? (r ^ 1) : r;
        float2 v = U2[c][pr];
        __syncthreads();
        U2[c][r] = v;
        __syncthreads();
      }
    }
  }

  // ---- Phase 2: A_w[j][k] = sum_i z_w[i] Re(conj(U_ij) U_ik) -------------
  {
    const int j = tid >> 4, k = tid & 15;
    float s0 = 0.f, s1 = 0.f, s2 = 0.f, s3 = 0.f;
    #pragma unroll
    for (int i = 0; i < 16; i++) {
      float2 uj = U2[j][i], uk = U2[k][i];
      float p = uj.x * uk.x + uj.y * uk.y;
      s0 += (i & 8) ? -p : p;
      s1 += (i & 4) ? -p : p;
      s2 += (i & 2) ? -p : p;
      s3 += (i & 1) ? -p : p;
    }
    A[0][j][k] = s0; A[1][j][k] = s1; A[2][j][k] = s2; A[3][j][k] = s3;
  }
  __syncthreads();

  // Basis per 2x2 block: f=0: .5(x00+x11)  f=1: .5(x00-x11)  f=2: .5(x01+x10)
  {  // Phase 3a: contract qubit0 (bit3)
    const int w = tid >> 6, j = (tid >> 3) & 7, k = tid & 7;
    float x00 = A[w][j][k],     x01 = A[w][j][k + 8];
    float x10 = A[w][j + 8][k], x11 = A[w][j + 8][k + 8];
    S1[w][0][j][k] = 0.5f * (x00 + x11);
    S1[w][1][j][k] = 0.5f * (x00 - x11);
    S1[w][2][j][k] = 0.5f * (x01 + x10);
  }
  __syncthreads();
  if (tid < 192) {  // Phase 3b: + qubit1
    const int w = tid / 48, r = tid % 48;
    const int f0 = r >> 4, j = (r >> 2) & 3, k = r & 3;
    float x00 = S1[w][f0][j][k],     x01 = S1[w][f0][j][k + 4];
    float x10 = S1[w][f0][j + 4][k], x11 = S1[w][f0][j + 4][k + 4];
    S2[w][f0][0][j][k] = 0.5f * (x00 + x11);
    S2[w][f0][1][j][k] = 0.5f * (x00 - x11);
    S2[w][f0][2][j][k] = 0.5f * (x01 + x10);
  }
  __syncthreads();
  if (tid < 144) {  // Phase 3c: + qubit2
    const int w = tid / 36, r = tid % 36;
    const int f0 = r / 12, f1 = (r >> 2) % 3, j = (r >> 1) & 1, k = r & 1;
    float x00 = S2[w][f0][f1][j][k],     x01 = S2[w][f0][f1][j][k + 2];
    float x10 = S2[w][f0][f1][j + 2][k], x11 = S2[w][f0][f1][j + 2][k + 2];
    S3[w][f0][f1][0][j][k] = 0.5f * (x00 + x11);
    S3[w][f0][f1][1][j][k] = 0.5f * (x00 - x11);
    S3[w][f0][f1][2][j][k] = 0.5f * (x01 + x10);
  }
  __syncthreads();
  if (tid < 108) {  // Phase 3d: + qubit3 -> float4 per (w,f0,f1,f2)
    const int w = tid / 27, r = tid % 27;
    const int f0 = r / 9, f1 = (r / 3) % 3, f2 = r % 3;
    float y00 = S3[w][f0][f1][f2][0][0], y01 = S3[w][f0][f1][f2][0][1];
    float y10 = S3[w][f0][f1][f2][1][0], y11 = S3[w][f0][f1][f2][1][1];
    float4 o;
    o.x = 0.5f * (y00 + y11);
    o.y = 0.5f * (y00 - y11);
    o.z = 0.5f * (y01 + y10);
    o.w = 0.f;
    coef_out[tid] = o;
  }
}

// ---- main kernel: coefficients via forced s_load into SGPR quads ----------

#define TRIGM(xv, U, V) { \
  float e_  = __builtin_amdgcn_exp2f((xv) * 2.8853900817779268f); \
  float th_ = 1.0f - 2.0f * __builtin_amdgcn_rcpf(e_ + 1.0f); \
  U = __builtin_amdgcn_cosf(th_ * 0.25f); \
  V = __builtin_amdgcn_sinf(th_ * 0.25f); }

#define SAMPLE_TRIG(K) \
  TRIGM(X##K.x, u0_##K, v0_##K) TRIGM(X##K.y, u1_##K, v1_##K) \
  TRIGM(X##K.z, u2_##K, v2_##K) TRIGM(X##K.w, u3_##K, v3_##K)

// 9 scalar loads (one e1-block of one wire) + drain, as ONE asm blob.
// Outputs are early-clobber SGPR quads (must not alias the address pair);
// consumers are data-dependent on the outputs so ordering is guaranteed.
#define SLOAD9(W, E1) \
  asm volatile( \
    "s_load_dwordx4 %0, %9, %10\n\t" \
    "s_load_dwordx4 %1, %9, %11\n\t" \
    "s_load_dwordx4 %2, %9, %12\n\t" \
    "s_load_dwordx4 %3, %9, %13\n\t" \
    "s_load_dwordx4 %4, %9, %14\n\t" \
    "s_load_dwordx4 %5, %9, %15\n\t" \
    "s_load_dwordx4 %6, %9, %16\n\t" \
    "s_load_dwordx4 %7, %9, %17\n\t" \
    "s_load_dwordx4 %8, %9, %18\n\t" \
    "s_waitcnt lgkmcnt(0)" \
    : "=&s"(c0), "=&s"(c1), "=&s"(c2), "=&s"(c3), "=&s"(c4), \
      "=&s"(c5), "=&s"(c6), "=&s"(c7), "=&s"(c8) \
    : "s"(coef), \
      "i"((((W) * 27 + (E1) * 9 + 0) * 16)), \
      "i"((((W) * 27 + (E1) * 9 + 1) * 16)), \
      "i"((((W) * 27 + (E1) * 9 + 2) * 16)), \
      "i"((((W) * 27 + (E1) * 9 + 3) * 16)), \
      "i"((((W) * 27 + (E1) * 9 + 4) * 16)), \
      "i"((((W) * 27 + (E1) * 9 + 5) * 16)), \
      "i"((((W) * 27 + (E1) * 9 + 6) * 16)), \
      "i"((((W) * 27 + (E1) * 9 + 7) * 16)), \
      "i"((((W) * 27 + (E1) * 9 + 8) * 16)));

#define ACC3C(C, E3, K) { \
  float t_ = fmaf((C).z, v3_##K, fmaf((C).y, u3_##K, (C).x)); \
  if ((E3) == 0) a3_##K = t_; \
  else a3_##K = fmaf(t_, ((E3) == 1) ? u2_##K : v2_##K, a3_##K); }

#define ACC2E(E2, K) { \
  if ((E2) == 0) a2_##K = a3_##K; \
  else a2_##K = fmaf(a3_##K, ((E2) == 1) ? u1_##K : v1_##K, a2_##K); }

#define ACC1E(E1, K) { \
  if ((E1) == 0) a1_##K = a2_##K; \
  else a1_##K = fmaf(a2_##K, ((E1) == 1) ? u0_##K : v0_##K, a1_##K); }

#define E2TRIPLE(CX, CY, CZ, E2) { \
  float a3_0, a3_1, a3_2, a3_3; \
  ACC3C(CX, 0, 0) ACC3C(CX, 0, 1) ACC3C(CX, 0, 2) ACC3C(CX, 0, 3) \
  ACC3C(CY, 1, 0) ACC3C(CY, 1, 1) ACC3C(CY, 1, 2) ACC3C(CY, 1, 3) \
  ACC3C(CZ, 2, 0) ACC3C(CZ, 2, 1) ACC3C(CZ, 2, 2) ACC3C(CZ, 2, 3) \
  ACC2E(E2, 0) ACC2E(E2, 1) ACC2E(E2, 2) ACC2E(E2, 3) }

#define E1BLOCK(W, E1) { \
  f4s c0, c1, c2, c3, c4, c5, c6, c7, c8; \
  SLOAD9(W, E1) \
  float a2_0, a2_1, a2_2, a2_3; \
  E2TRIPLE(c0, c1, c2, 0) E2TRIPLE(c3, c4, c5, 1) E2TRIPLE(c6, c7, c8, 2) \
  ACC1E(E1, 0) ACC1E(E1, 1) ACC1E(E1, 2) ACC1E(E1, 3) }

#define CONTRACT(W) { \
  float a1_0, a1_1, a1_2, a1_3; \
  E1BLOCK(W, 0) E1BLOCK(W, 1) E1BLOCK(W, 2) \
  o##W##_0 = a1_0; o##W##_1 = a1_1; o##W##_2 = a1_2; o##W##_3 = a1_3; }

__global__ __launch_bounds__(256) void qel_main(const float4* __restrict__ x4,
                                                float4* __restrict__ out4,
                                                const float4* __restrict__ coef,
                                                int quarter) {
  const int tid = threadIdx.x;
  const int gid = blockIdx.x * 256 + tid;
  const bool act = gid < quarter;
  const int g = act ? gid : 0;

  // Sample loads issued first; HBM latency hides under the trig block.
  float4 X0 = x4[g];
  float4 X1 = x4[g + quarter];
  float4 X2 = x4[g + 2 * quarter];
  float4 X3 = x4[g + 3 * quarter];

  float u0_0, v0_0, u1_0, v1_0, u2_0, v2_0, u3_0, v3_0;
  float u0_1, v0_1, u1_1, v1_1, u2_1, v2_1, u3_1, v3_1;
  float u0_2, v0_2, u1_2, v1_2, u2_2, v2_2, u3_2, v3_2;
  float u0_3, v0_3, u1_3, v1_3, u2_3, v2_3, u3_3, v3_3;
  SAMPLE_TRIG(0) SAMPLE_TRIG(1) SAMPLE_TRIG(2) SAMPLE_TRIG(3)

  float o0_0, o0_1, o0_2, o0_3;
  float o1_0, o1_1, o1_2, o1_3;
  float o2_0, o2_1, o2_2, o2_3;
  float o3_0, o3_1, o3_2, o3_3;

  CONTRACT(0) CONTRACT(1) CONTRACT(2) CONTRACT(3)

  if (act) {
    out4[gid]               = make_float4(o0_0, o1_0, o2_0, o3_0);
    out4[gid + quarter]     = make_float4(o0_1, o1_1, o2_1, o3_1);
    out4[gid + 2 * quarter] = make_float4(o0_2, o1_2, o2_2, o3_2);
    out4[gid + 3 * quarter] = make_float4(o0_3, o1_3, o2_3, o3_3);
  }
}

// ---------------------------------------------------------------------------

extern "C" void kernel_launch(void* const* d_in, const int* in_sizes, int n_in,
                              void* d_out, int out_size, void* d_ws, size_t ws_size,
                              hipStream_t stream) {
  const float* x      = (const float*)d_in[0];   // [B,4] f32
  const float* params = (const float*)d_in[1];   // [2,4,3] f32
  float* out = (float*)d_out;                    // [B,4] f32
  float4* coef = (float4*)d_ws;                  // 108 float4 in workspace

  int B = in_sizes[0] / 4;
  int quarter = B / 4;
  int blocks = (quarter + 255) / 256;

  qel_setup<<<1, 256, 0, stream>>>(params, coef);
  qel_main<<<blocks, 256, 0, stream>>>((const float4*)x, (float4*)out,
                                       (const float4*)coef, quarter);
}

// Round 14
// 22.995 us; speedup vs baseline: 8.0419x; 1.6303x over previous
//
#include <hip/hip_runtime.h>

// ---------------------------------------------------------------------------
// QuantumEntanglementLayer: 4 qubits, DIM=16, BATCH=2^20.
// out[b][w] = s^T A_w s,  A_w = Re(U^H Z_w U),  s = tensor prod of RY(|0>).
// Reduced to 4 multilinear polynomials with 81 coeffs each in (1,u_w,v_w),
// u_w = cos(tanh(x_w)*pi/2), v_w = sin(tanh(x_w)*pi/2).
//
// Main-kernel history: a stubborn ~23us resists every coefficient transport
// (global 39.0 / LDS 34.8 / kernel-arg 39.5 / s_load 37.5) and work shape
// (4 vs 8 samples/thread). Common denominator: fully-unrolled ~14KB
// straight-line body -> scheduler balloons liveness to 240-256 VGPR
// (2 waves/SIMD) and the front-end streams cold code once per thread.
// This revision ROLLS the W (wire) and e1 loops (#pragma unroll 1): ~1KB
// body executed 12x, hoist window structurally bounded to 9 float4 ->
// natural VGPR ~90-130 with no attribute (all attributes measured poison).
// Runtime-W outputs go through private LDS slots (rule-#20-safe), gathered
// into float4 stores at the end. Coefficients stay on the proven LDS path.
// ---------------------------------------------------------------------------

__device__ __forceinline__ float hwsin(float rad) {
  return __builtin_amdgcn_sinf(rad * 0.15915494309189535f);  // rad -> rev
}
__device__ __forceinline__ float hwcos(float rad) {
  return __builtin_amdgcn_cosf(rad * 0.15915494309189535f);
}

__global__ __launch_bounds__(256) void qel_setup(const float* __restrict__ params,
                                                 float4* __restrict__ coef_out) {
  __shared__ float2 U2[16][17];            // circuit state [col][row], +1 pad
  __shared__ float A[4][16][16];           // A_w
  __shared__ float S1[4][3][8][8];         // after contracting qubit0 (f0)
  __shared__ float S2[4][3][3][4][4];      // + qubit1 (f1)
  __shared__ float S3[4][3][3][3][2][2];   // + qubit2 (f2)
  const int tid = threadIdx.x;

  // ---- Phase 1 (LDS-parallel): U = circuit, one element per thread -------
  {
    const int c = tid >> 4, r = tid & 15;
    U2[c][r] = make_float2((r == c) ? 1.f : 0.f, 0.f);
    __syncthreads();

    #pragma unroll
    for (int layer = 0; layer < 2; layer++) {
      #pragma unroll
      for (int i = 0; i < 3; i++) {        // CNOT(i,i+1): cm=8>>i, tm=4>>i
        const int cm = 8 >> i, tm = 4 >> i;
        const int pr = (r & cm) ? (r ^ tm) : r;
        float2 v = U2[c][pr];
        __syncthreads();
        U2[c][r] = v;
        __syncthreads();
      }
      #pragma unroll
      for (int w = 0; w < 4; w++) {        // Rot(phi,theta,omega) on wire w
        float phi   = params[layer * 12 + w * 3 + 0];
        float theta = params[layer * 12 + w * 3 + 1];
        float omega = params[layer * 12 + w * 3 + 2];
        float ct = hwcos(theta * 0.5f), st = hwsin(theta * 0.5f);
        float ap = -0.5f * (phi + omega), am = 0.5f * (phi - omega);
        float g00r =  hwcos(ap) * ct, g00i =  hwsin(ap) * ct;
        float g01r = -hwcos(am) * st, g01i = -hwsin(am) * st;
        float g10r =  hwcos(am) * st, g10i = -hwsin(am) * st;
        float g11r =  g00r,           g11i = -g00i;
        const int tm = 8 >> w;
        const int r0 = r & ~tm, r1 = r | tm;
        const bool hi = (r & tm) != 0;
        float gar = hi ? g10r : g00r, gai = hi ? g10i : g00i;
        float gbr = hi ? g11r : g01r, gbi = hi ? g11i : g01i;
        float2 o0 = U2[c][r0], o1 = U2[c][r1];
        __syncthreads();
        float nr = gar * o0.x - gai * o0.y + gbr * o1.x - gbi * o1.y;
        float ni = gar * o0.y + gai * o0.x + gbr * o1.y + gbi * o1.x;
        U2[c][r] = make_float2(nr, ni);
        __syncthreads();
      }
      {                                    // CNOT(0,3): cm=8, tm=1
        const int pr = (r & 8) ? (r ^ 1) : r;
        float2 v = U2[c][pr];
        __syncthreads();
        U2[c][r] = v;
        __syncthreads();
      }
    }
  }

  // ---- Phase 2: A_w[j][k] = sum_i z_w[i] Re(conj(U_ij) U_ik) -------------
  {
    const int j = tid >> 4, k = tid & 15;
    float s0 = 0.f, s1 = 0.f, s2 = 0.f, s3 = 0.f;
    #pragma unroll
    for (int i = 0; i < 16; i++) {
      float2 uj = U2[j][i], uk = U2[k][i];
      float p = uj.x * uk.x + uj.y * uk.y;
      s0 += (i & 8) ? -p : p;
      s1 += (i & 4) ? -p : p;
      s2 += (i & 2) ? -p : p;
      s3 += (i & 1) ? -p : p;
    }
    A[0][j][k] = s0; A[1][j][k] = s1; A[2][j][k] = s2; A[3][j][k] = s3;
  }
  __syncthreads();

  // Basis per 2x2 block: f=0: .5(x00+x11)  f=1: .5(x00-x11)  f=2: .5(x01+x10)
  {  // Phase 3a: contract qubit0 (bit3)
    const int w = tid >> 6, j = (tid >> 3) & 7, k = tid & 7;
    float x00 = A[w][j][k],     x01 = A[w][j][k + 8];
    float x10 = A[w][j + 8][k], x11 = A[w][j + 8][k + 8];
    S1[w][0][j][k] = 0.5f * (x00 + x11);
    S1[w][1][j][k] = 0.5f * (x00 - x11);
    S1[w][2][j][k] = 0.5f * (x01 + x10);
  }
  __syncthreads();
  if (tid < 192) {  // Phase 3b: + qubit1
    const int w = tid / 48, r = tid % 48;
    const int f0 = r >> 4, j = (r >> 2) & 3, k = r & 3;
    float x00 = S1[w][f0][j][k],     x01 = S1[w][f0][j][k + 4];
    float x10 = S1[w][f0][j + 4][k], x11 = S1[w][f0][j + 4][k + 4];
    S2[w][f0][0][j][k] = 0.5f * (x00 + x11);
    S2[w][f0][1][j][k] = 0.5f * (x00 - x11);
    S2[w][f0][2][j][k] = 0.5f * (x01 + x10);
  }
  __syncthreads();
  if (tid < 144) {  // Phase 3c: + qubit2
    const int w = tid / 36, r = tid % 36;
    const int f0 = r / 12, f1 = (r >> 2) % 3, j = (r >> 1) & 1, k = r & 1;
    float x00 = S2[w][f0][f1][j][k],     x01 = S2[w][f0][f1][j][k + 2];
    float x10 = S2[w][f0][f1][j + 2][k], x11 = S2[w][f0][f1][j + 2][k + 2];
    S3[w][f0][f1][0][j][k] = 0.5f * (x00 + x11);
    S3[w][f0][f1][1][j][k] = 0.5f * (x00 - x11);
    S3[w][f0][f1][2][j][k] = 0.5f * (x01 + x10);
  }
  __syncthreads();
  if (tid < 108) {  // Phase 3d: + qubit3 -> float4 per (w,f0,f1,f2)
    const int w = tid / 27, r = tid % 27;
    const int f0 = r / 9, f1 = (r / 3) % 3, f2 = r % 3;
    float y00 = S3[w][f0][f1][f2][0][0], y01 = S3[w][f0][f1][f2][0][1];
    float y10 = S3[w][f0][f1][f2][1][0], y11 = S3[w][f0][f1][f2][1][1];
    float4 o;
    o.x = 0.5f * (y00 + y11);
    o.y = 0.5f * (y00 - y11);
    o.z = 0.5f * (y01 + y10);
    o.w = 0.f;
    coef_out[tid] = o;
  }
}

// ---- main kernel: rolled W/e1 loops, LDS coefficients, LDS output slots ---

#define TRIGM(xv, U, V) { \
  float e_  = __builtin_amdgcn_exp2f((xv) * 2.8853900817779268f); \
  float th_ = 1.0f - 2.0f * __builtin_amdgcn_rcpf(e_ + 1.0f); \
  U = __builtin_amdgcn_cosf(th_ * 0.25f); \
  V = __builtin_amdgcn_sinf(th_ * 0.25f); }

#define SAMPLE_TRIG(K) \
  TRIGM(X##K.x, u0_##K, v0_##K) TRIGM(X##K.y, u1_##K, v1_##K) \
  TRIGM(X##K.z, u2_##K, v2_##K) TRIGM(X##K.w, u3_##K, v3_##K)

#define ACC3(K) { \
  float t_ = fmaf(c.z, v3_##K, fmaf(c.y, u3_##K, c.x)); \
  if (e3 == 0) a3_##K = t_; \
  else a3_##K = fmaf(t_, (e3 == 1) ? u2_##K : v2_##K, a3_##K); }

#define ACC2(K) { \
  if (e2 == 0) a2_##K = a3_##K; \
  else a2_##K = fmaf(a3_##K, (e2 == 1) ? u1_##K : v1_##K, a2_##K); }

// e1 is a RUNTIME loop index here: select via cndmask, guard via select.
#define ACC1R(K) { \
  float m_ = (e1 == 1) ? u0_##K : v0_##K; \
  a1_##K = (e1 == 0) ? a2_##K : fmaf(a2_##K, m_, a1_##K); }

__global__ __launch_bounds__(256) void qel_main(const float4* __restrict__ x4,
                                                float4* __restrict__ out4,
                                                const float4* __restrict__ coef,
                                                int quarter) {
  __shared__ float4 Cs[108];
  __shared__ float Olds[4][4][256];   // [wire][sample][tid] private slots
  const int tid = threadIdx.x;
  const int gid = blockIdx.x * 256 + tid;
  const bool act = gid < quarter;
  const int g = act ? gid : 0;

  // Sample + coefficient loads first; latency hides under the trig block.
  float4 X0 = x4[g];
  float4 X1 = x4[g + quarter];
  float4 X2 = x4[g + 2 * quarter];
  float4 X3 = x4[g + 3 * quarter];

  float4 cstage;
  if (tid < 108) cstage = coef[tid];

  float u0_0, v0_0, u1_0, v1_0, u2_0, v2_0, u3_0, v3_0;
  float u0_1, v0_1, u1_1, v1_1, u2_1, v2_1, u3_1, v3_1;
  float u0_2, v0_2, u1_2, v1_2, u2_2, v2_2, u3_2, v3_2;
  float u0_3, v0_3, u1_3, v1_3, u2_3, v2_3, u3_3, v3_3;
  SAMPLE_TRIG(0) SAMPLE_TRIG(1) SAMPLE_TRIG(2) SAMPLE_TRIG(3)

  if (tid < 108) Cs[tid] = cstage;
  __syncthreads();

  #pragma unroll 1
  for (int W = 0; W < 4; W++) {
    float a1_0 = 0.f, a1_1 = 0.f, a1_2 = 0.f, a1_3 = 0.f;
    #pragma unroll 1
    for (int e1 = 0; e1 < 3; e1++) {
      const float4* cb = &Cs[W * 27 + e1 * 9];   // runtime base, imm offsets
      float a2_0, a2_1, a2_2, a2_3;
      #pragma unroll
      for (int e2 = 0; e2 < 3; e2++) {
        float a3_0, a3_1, a3_2, a3_3;
        #pragma unroll
        for (int e3 = 0; e3 < 3; e3++) {
          float4 c = cb[e2 * 3 + e3];
          ACC3(0) ACC3(1) ACC3(2) ACC3(3)
        }
        ACC2(0) ACC2(1) ACC2(2) ACC2(3)
      }
      ACC1R(0) ACC1R(1) ACC1R(2) ACC1R(3)
    }
    Olds[W][0][tid] = a1_0;
    Olds[W][1][tid] = a1_1;
    Olds[W][2][tid] = a1_2;
    Olds[W][3][tid] = a1_3;
  }

  // Same-thread LDS slots: no barrier needed (compiler inserts lgkmcnt).
  if (act) {
    out4[gid]               = make_float4(Olds[0][0][tid], Olds[1][0][tid],
                                          Olds[2][0][tid], Olds[3][0][tid]);
    out4[gid + quarter]     = make_float4(Olds[0][1][tid], Olds[1][1][tid],
                                          Olds[2][1][tid], Olds[3][1][tid]);
    out4[gid + 2 * quarter] = make_float4(Olds[0][2][tid], Olds[1][2][tid],
                                          Olds[2][2][tid], Olds[3][2][tid]);
    out4[gid + 3 * quarter] = make_float4(Olds[0][3][tid], Olds[1][3][tid],
                                          Olds[2][3][tid], Olds[3][3][tid]);
  }
}

// ---------------------------------------------------------------------------

extern "C" void kernel_launch(void* const* d_in, const int* in_sizes, int n_in,
                              void* d_out, int out_size, void* d_ws, size_t ws_size,
                              hipStream_t stream) {
  const float* x      = (const float*)d_in[0];   // [B,4] f32
  const float* params = (const float*)d_in[1];   // [2,4,3] f32
  float* out = (float*)d_out;                    // [B,4] f32
  float4* coef = (float4*)d_ws;                  // 108 float4 in workspace

  int B = in_sizes[0] / 4;
  int quarter = B / 4;
  int blocks = (quarter + 255) / 256;

  qel_setup<<<1, 256, 0, stream>>>(params, coef);
  qel_main<<<blocks, 256, 0, stream>>>((const float4*)x, (float4*)out,
                                       (const float4*)coef, quarter);
}

// Round 15
// 21.495 us; speedup vs baseline: 8.6032x; 1.0698x over previous
//
#include <hip/hip_runtime.h>

// ---------------------------------------------------------------------------
// QuantumEntanglementLayer: 4 qubits, DIM=16, BATCH=2^20.
// out[b][w] = s^T A_w s,  A_w = Re(U^H Z_w U),  s = tensor prod of RY(|0>).
// Reduced to 4 multilinear polynomials with 81 coeffs each in (1,u_w,v_w),
// u_w = cos(tanh(x_w)*pi/2), v_w = sin(tanh(x_w)*pi/2).
//
// History: rolled W/e1 contract (r14) fixed the VGPR balloon structurally
// (unrolled 14KB body -> 240-256 VGPR -> 2 waves/SIMD; rolled 1KB body ->
// natural bound, main 22.9 -> ~11us, total 34.8 -> 23.0). Remaining ~10-11us
// is two-dispatch launch/serialization overhead. This revision: FUSE with
// the rolled body (earlier fusions failed only because of the unrolled
// contract). Per-block LDS-parallel circuit setup (~1-2us, overlaps across
// blocks), Cs straight into LDS, single dispatch.
// ---------------------------------------------------------------------------

__device__ __forceinline__ float hwsin(float rad) {
  return __builtin_amdgcn_sinf(rad * 0.15915494309189535f);  // rad -> rev
}
__device__ __forceinline__ float hwcos(float rad) {
  return __builtin_amdgcn_cosf(rad * 0.15915494309189535f);
}

#define TRIGM(xv, U, V) { \
  float e_  = __builtin_amdgcn_exp2f((xv) * 2.8853900817779268f); \
  float th_ = 1.0f - 2.0f * __builtin_amdgcn_rcpf(e_ + 1.0f); \
  U = __builtin_amdgcn_cosf(th_ * 0.25f); \
  V = __builtin_amdgcn_sinf(th_ * 0.25f); }

#define SAMPLE_TRIG(K) \
  TRIGM(X##K.x, u0_##K, v0_##K) TRIGM(X##K.y, u1_##K, v1_##K) \
  TRIGM(X##K.z, u2_##K, v2_##K) TRIGM(X##K.w, u3_##K, v3_##K)

#define ACC3(K) { \
  float t_ = fmaf(c.z, v3_##K, fmaf(c.y, u3_##K, c.x)); \
  if (e3 == 0) a3_##K = t_; \
  else a3_##K = fmaf(t_, (e3 == 1) ? u2_##K : v2_##K, a3_##K); }

#define ACC2(K) { \
  if (e2 == 0) a2_##K = a3_##K; \
  else a2_##K = fmaf(a3_##K, (e2 == 1) ? u1_##K : v1_##K, a2_##K); }

// e1 is a RUNTIME loop index: select via cndmask, guard via select.
#define ACC1R(K) { \
  float m_ = (e1 == 1) ? u0_##K : v0_##K; \
  a1_##K = (e1 == 0) ? a2_##K : fmaf(a2_##K, m_, a1_##K); }

__global__ __launch_bounds__(256) void qel_fused(const float4* __restrict__ x4,
                                                 const float* __restrict__ params,
                                                 float4* __restrict__ out4,
                                                 int quarter) {
  __shared__ float2 U2[16][17];            // circuit state [col][row], +1 pad
  __shared__ float A[4][16][16];           // A_w
  __shared__ float S1[4][3][8][8];         // after contracting qubit0 (f0)
  __shared__ float S2[4][3][3][4][4];      // + qubit1 (f1)
  __shared__ float S3[4][3][3][3][2][2];   // + qubit2 (f2)
  __shared__ float4 Cs[108];               // final coefficients
  __shared__ float Olds[4][4][256];        // [wire][sample][tid] out slots

  const int tid = threadIdx.x;
  const int gid = blockIdx.x * 256 + tid;
  const bool act = gid < quarter;
  const int g = act ? gid : 0;

  // Sample loads first: 16 regs live across the lean setup; HBM latency
  // hides under the circuit + contraction-prep phases.
  float4 X0 = x4[g];
  float4 X1 = x4[g + quarter];
  float4 X2 = x4[g + 2 * quarter];
  float4 X3 = x4[g + 3 * quarter];

  // ---- Setup phase 1 (LDS-parallel): U = circuit, one element/thread -----
  {
    const int c = tid >> 4, r = tid & 15;
    U2[c][r] = make_float2((r == c) ? 1.f : 0.f, 0.f);
    __syncthreads();

    #pragma unroll
    for (int layer = 0; layer < 2; layer++) {
      #pragma unroll
      for (int i = 0; i < 3; i++) {        // CNOT(i,i+1): cm=8>>i, tm=4>>i
        const int cm = 8 >> i, tm = 4 >> i;
        const int pr = (r & cm) ? (r ^ tm) : r;
        float2 v = U2[c][pr];
        __syncthreads();
        U2[c][r] = v;
        __syncthreads();
      }
      #pragma unroll
      for (int w = 0; w < 4; w++) {        // Rot(phi,theta,omega) on wire w
        float phi   = params[layer * 12 + w * 3 + 0];
        float theta = params[layer * 12 + w * 3 + 1];
        float omega = params[layer * 12 + w * 3 + 2];
        float ct = hwcos(theta * 0.5f), st = hwsin(theta * 0.5f);
        float ap = -0.5f * (phi + omega), am = 0.5f * (phi - omega);
        float g00r =  hwcos(ap) * ct, g00i =  hwsin(ap) * ct;
        float g01r = -hwcos(am) * st, g01i = -hwsin(am) * st;
        float g10r =  hwcos(am) * st, g10i = -hwsin(am) * st;
        float g11r =  g00r,           g11i = -g00i;
        const int tm = 8 >> w;
        const int r0 = r & ~tm, r1 = r | tm;
        const bool hi = (r & tm) != 0;
        float gar = hi ? g10r : g00r, gai = hi ? g10i : g00i;
        float gbr = hi ? g11r : g01r, gbi = hi ? g11i : g01i;
        float2 o0 = U2[c][r0], o1 = U2[c][r1];
        __syncthreads();
        float nr = gar * o0.x - gai * o0.y + gbr * o1.x - gbi * o1.y;
        float ni = gar * o0.y + gai * o0.x + gbr * o1.y + gbi * o1.x;
        U2[c][r] = make_float2(nr, ni);
        __syncthreads();
      }
      {                                    // CNOT(0,3): cm=8, tm=1
        const int pr = (r & 8) ? (r ^ 1) : r;
        float2 v = U2[c][pr];
        __syncthreads();
        U2[c][r] = v;
        __syncthreads();
      }
    }
  }

  // ---- Setup phase 2: A_w[j][k] = sum_i z_w[i] Re(conj(U_ij) U_ik) -------
  {
    const int j = tid >> 4, k = tid & 15;
    float s0 = 0.f, s1 = 0.f, s2 = 0.f, s3 = 0.f;
    #pragma unroll
    for (int i = 0; i < 16; i++) {
      float2 uj = U2[j][i], uk = U2[k][i];
      float p = uj.x * uk.x + uj.y * uk.y;
      s0 += (i & 8) ? -p : p;
      s1 += (i & 4) ? -p : p;
      s2 += (i & 2) ? -p : p;
      s3 += (i & 1) ? -p : p;
    }
    A[0][j][k] = s0; A[1][j][k] = s1; A[2][j][k] = s2; A[3][j][k] = s3;
  }
  __syncthreads();

  // Basis per 2x2 block: f=0: .5(x00+x11)  f=1: .5(x00-x11)  f=2: .5(x01+x10)
  {  // Phase 3a: contract qubit0 (bit3)
    const int w = tid >> 6, j = (tid >> 3) & 7, k = tid & 7;
    float x00 = A[w][j][k],     x01 = A[w][j][k + 8];
    float x10 = A[w][j + 8][k], x11 = A[w][j + 8][k + 8];
    S1[w][0][j][k] = 0.5f * (x00 + x11);
    S1[w][1][j][k] = 0.5f * (x00 - x11);
    S1[w][2][j][k] = 0.5f * (x01 + x10);
  }
  __syncthreads();
  if (tid < 192) {  // Phase 3b: + qubit1
    const int w = tid / 48, r = tid % 48;
    const int f0 = r >> 4, j = (r >> 2) & 3, k = r & 3;
    float x00 = S1[w][f0][j][k],     x01 = S1[w][f0][j][k + 4];
    float x10 = S1[w][f0][j + 4][k], x11 = S1[w][f0][j + 4][k + 4];
    S2[w][f0][0][j][k] = 0.5f * (x00 + x11);
    S2[w][f0][1][j][k] = 0.5f * (x00 - x11);
    S2[w][f0][2][j][k] = 0.5f * (x01 + x10);
  }
  __syncthreads();
  if (tid < 144) {  // Phase 3c: + qubit2
    const int w = tid / 36, r = tid % 36;
    const int f0 = r / 12, f1 = (r >> 2) % 3, j = (r >> 1) & 1, k = r & 1;
    float x00 = S2[w][f0][f1][j][k],     x01 = S2[w][f0][f1][j][k + 2];
    float x10 = S2[w][f0][f1][j + 2][k], x11 = S2[w][f0][f1][j + 2][k + 2];
    S3[w][f0][f1][0][j][k] = 0.5f * (x00 + x11);
    S3[w][f0][f1][1][j][k] = 0.5f * (x00 - x11);
    S3[w][f0][f1][2][j][k] = 0.5f * (x01 + x10);
  }
  __syncthreads();
  if (tid < 108) {  // Phase 3d: + qubit3 -> float4 per (w,f0,f1,f2)
    const int w = tid / 27, r = tid % 27;
    const int f0 = r / 9, f1 = (r / 3) % 3, f2 = r % 3;
    float y00 = S3[w][f0][f1][f2][0][0], y01 = S3[w][f0][f1][f2][0][1];
    float y10 = S3[w][f0][f1][f2][1][0], y11 = S3[w][f0][f1][f2][1][1];
    float4 o;
    o.x = 0.5f * (y00 + y11);
    o.y = 0.5f * (y00 - y11);
    o.z = 0.5f * (y01 + y10);
    o.w = 0.f;
    Cs[tid] = o;
  }

  // ---- Per-sample trig (all threads, before the final barrier) -----------
  float u0_0, v0_0, u1_0, v1_0, u2_0, v2_0, u3_0, v3_0;
  float u0_1, v0_1, u1_1, v1_1, u2_1, v2_1, u3_1, v3_1;
  float u0_2, v0_2, u1_2, v1_2, u2_2, v2_2, u3_2, v3_2;
  float u0_3, v0_3, u1_3, v1_3, u2_3, v2_3, u3_3, v3_3;
  SAMPLE_TRIG(0) SAMPLE_TRIG(1) SAMPLE_TRIG(2) SAMPLE_TRIG(3)

  __syncthreads();

  // ---- Rolled polynomial contraction (r14 body, verbatim) ----------------
  #pragma unroll 1
  for (int W = 0; W < 4; W++) {
    float a1_0 = 0.f, a1_1 = 0.f, a1_2 = 0.f, a1_3 = 0.f;
    #pragma unroll 1
    for (int e1 = 0; e1 < 3; e1++) {
      const float4* cb = &Cs[W * 27 + e1 * 9];   // runtime base, imm offsets
      float a2_0, a2_1, a2_2, a2_3;
      #pragma unroll
      for (int e2 = 0; e2 < 3; e2++) {
        float a3_0, a3_1, a3_2, a3_3;
        #pragma unroll
        for (int e3 = 0; e3 < 3; e3++) {
          float4 c = cb[e2 * 3 + e3];
          ACC3(0) ACC3(1) ACC3(2) ACC3(3)
        }
        ACC2(0) ACC2(1) ACC2(2) ACC2(3)
      }
      ACC1R(0) ACC1R(1) ACC1R(2) ACC1R(3)
    }
    Olds[W][0][tid] = a1_0;
    Olds[W][1][tid] = a1_1;
    Olds[W][2][tid] = a1_2;
    Olds[W][3][tid] = a1_3;
  }

  // Same-thread LDS slots: no barrier needed (compiler inserts lgkmcnt).
  if (act) {
    out4[gid]               = make_float4(Olds[0][0][tid], Olds[1][0][tid],
                                          Olds[2][0][tid], Olds[3][0][tid]);
    out4[gid + quarter]     = make_float4(Olds[0][1][tid], Olds[1][1][tid],
                                          Olds[2][1][tid], Olds[3][1][tid]);
    out4[gid + 2 * quarter] = make_float4(Olds[0][2][tid], Olds[1][2][tid],
                                          Olds[2][2][tid], Olds[3][2][tid]);
    out4[gid + 3 * quarter] = make_float4(Olds[0][3][tid], Olds[1][3][tid],
                                          Olds[2][3][tid], Olds[3][3][tid]);
  }
}

// ---------------------------------------------------------------------------

extern "C" void kernel_launch(void* const* d_in, const int* in_sizes, int n_in,
                              void* d_out, int out_size, void* d_ws, size_t ws_size,
                              hipStream_t stream) {
  const float* x      = (const float*)d_in[0];   // [B,4] f32
  const float* params = (const float*)d_in[1];   // [2,4,3] f32
  float* out = (float*)d_out;                    // [B,4] f32

  int B = in_sizes[0] / 4;
  int quarter = B / 4;
  int blocks = (quarter + 255) / 256;

  qel_fused<<<blocks, 256, 0, stream>>>((const float4*)x, params,
                                        (float4*)out, quarter);
}

// Round 16
// 20.589 us; speedup vs baseline: 8.9816x; 1.0440x over previous
//
#include <hip/hip_runtime.h>

// ---------------------------------------------------------------------------
// QuantumEntanglementLayer: 4 qubits, DIM=16, BATCH=2^20.
// out[b][w] = s^T A_w s,  A_w = Re(U^H Z_w U),  s = tensor prod of RY(|0>).
// Reduced to 4 multilinear polynomials with 81 coeffs each in (1,u_w,v_w),
// u_w = cos(tanh(x_w)*pi/2), v_w = sin(tanh(x_w)*pi/2).
//
// History: rolled W/e1 contract killed the VGPR balloon (r14: 34.8->23.0);
// fusing with the rolled body killed the 2-dispatch overhead (r15: ->21.5).
// Contract now sits at ~11us vs ~3.3us VALU floor, matching the LDS-return
// model (16 waves/CU x 108 uniform ds_read_b128 ~ 8.7us/CU). This revision:
// 8 samples/thread (512 blocks) -- halves chip-wide LDS coefficient traffic
// and doubles FMA chains per read. (r7's null 8-sample test ran in the
// 2-wave unrolled regime where residency, not LDS, was binding.)
// ---------------------------------------------------------------------------

__device__ __forceinline__ float hwsin(float rad) {
  return __builtin_amdgcn_sinf(rad * 0.15915494309189535f);  // rad -> rev
}
__device__ __forceinline__ float hwcos(float rad) {
  return __builtin_amdgcn_cosf(rad * 0.15915494309189535f);
}

#define TRIGM(xv, U, V) { \
  float e_  = __builtin_amdgcn_exp2f((xv) * 2.8853900817779268f); \
  float th_ = 1.0f - 2.0f * __builtin_amdgcn_rcpf(e_ + 1.0f); \
  U = __builtin_amdgcn_cosf(th_ * 0.25f); \
  V = __builtin_amdgcn_sinf(th_ * 0.25f); }

#define SAMPLE_TRIG(K) \
  TRIGM(X##K.x, u0_##K, v0_##K) TRIGM(X##K.y, u1_##K, v1_##K) \
  TRIGM(X##K.z, u2_##K, v2_##K) TRIGM(X##K.w, u3_##K, v3_##K)

#define DECL_TRIG(K) \
  float u0_##K, v0_##K, u1_##K, v1_##K, u2_##K, v2_##K, u3_##K, v3_##K;

#define ACC3(K) { \
  float t_ = fmaf(c.z, v3_##K, fmaf(c.y, u3_##K, c.x)); \
  if (e3 == 0) a3_##K = t_; \
  else a3_##K = fmaf(t_, (e3 == 1) ? u2_##K : v2_##K, a3_##K); }

#define ACC2(K) { \
  if (e2 == 0) a2_##K = a3_##K; \
  else a2_##K = fmaf(a3_##K, (e2 == 1) ? u1_##K : v1_##K, a2_##K); }

// e1 is a RUNTIME loop index: select via cndmask, guard via select.
#define ACC1R(K) { \
  float m_ = (e1 == 1) ? u0_##K : v0_##K; \
  a1_##K = (e1 == 0) ? a2_##K : fmaf(a2_##K, m_, a1_##K); }

#define ALL8(M) M(0) M(1) M(2) M(3) M(4) M(5) M(6) M(7)

__global__ __launch_bounds__(256) void qel_fused(const float4* __restrict__ x4,
                                                 const float* __restrict__ params,
                                                 float4* __restrict__ out4,
                                                 int eighth) {
  __shared__ float2 U2[16][17];            // circuit state [col][row], +1 pad
  __shared__ float A[4][16][16];           // A_w
  __shared__ float S1[4][3][8][8];         // after contracting qubit0 (f0)
  __shared__ float S2[4][3][3][4][4];      // + qubit1 (f1)
  __shared__ float S3[4][3][3][3][2][2];   // + qubit2 (f2)
  __shared__ float4 Cs[108];               // final coefficients
  __shared__ float Olds[4][8][256];        // [wire][sample][tid] out slots

  const int tid = threadIdx.x;
  const int gid = blockIdx.x * 256 + tid;
  const bool act = gid < eighth;
  const int g = act ? gid : 0;

  // Sample loads first: HBM latency hides under the circuit phases.
  float4 X0 = x4[g];
  float4 X1 = x4[g + eighth];
  float4 X2 = x4[g + 2 * eighth];
  float4 X3 = x4[g + 3 * eighth];
  float4 X4 = x4[g + 4 * eighth];
  float4 X5 = x4[g + 5 * eighth];
  float4 X6 = x4[g + 6 * eighth];
  float4 X7 = x4[g + 7 * eighth];

  // ---- Setup phase 1 (LDS-parallel): U = circuit, one element/thread -----
  {
    const int c = tid >> 4, r = tid & 15;
    U2[c][r] = make_float2((r == c) ? 1.f : 0.f, 0.f);
    __syncthreads();

    #pragma unroll
    for (int layer = 0; layer < 2; layer++) {
      #pragma unroll
      for (int i = 0; i < 3; i++) {        // CNOT(i,i+1): cm=8>>i, tm=4>>i
        const int cm = 8 >> i, tm = 4 >> i;
        const int pr = (r & cm) ? (r ^ tm) : r;
        float2 v = U2[c][pr];
        __syncthreads();
        U2[c][r] = v;
        __syncthreads();
      }
      #pragma unroll
      for (int w = 0; w < 4; w++) {        // Rot(phi,theta,omega) on wire w
        float phi   = params[layer * 12 + w * 3 + 0];
        float theta = params[layer * 12 + w * 3 + 1];
        float omega = params[layer * 12 + w * 3 + 2];
        float ct = hwcos(theta * 0.5f), st = hwsin(theta * 0.5f);
        float ap = -0.5f * (phi + omega), am = 0.5f * (phi - omega);
        float g00r =  hwcos(ap) * ct, g00i =  hwsin(ap) * ct;
        float g01r = -hwcos(am) * st, g01i = -hwsin(am) * st;
        float g10r =  hwcos(am) * st, g10i = -hwsin(am) * st;
        float g11r =  g00r,           g11i = -g00i;
        const int tm = 8 >> w;
        const int r0 = r & ~tm, r1 = r | tm;
        const bool hi = (r & tm) != 0;
        float gar = hi ? g10r : g00r, gai = hi ? g10i : g00i;
        float gbr = hi ? g11r : g01r, gbi = hi ? g11i : g01i;
        float2 o0 = U2[c][r0], o1 = U2[c][r1];
        __syncthreads();
        float nr = gar * o0.x - gai * o0.y + gbr * o1.x - gbi * o1.y;
        float ni = gar * o0.y + gai * o0.x + gbr * o1.y + gbi * o1.x;
        U2[c][r] = make_float2(nr, ni);
        __syncthreads();
      }
      {                                    // CNOT(0,3): cm=8, tm=1
        const int pr = (r & 8) ? (r ^ 1) : r;
        float2 v = U2[c][pr];
        __syncthreads();
        U2[c][r] = v;
        __syncthreads();
      }
    }
  }

  // ---- Setup phase 2: A_w[j][k] = sum_i z_w[i] Re(conj(U_ij) U_ik) -------
  {
    const int j = tid >> 4, k = tid & 15;
    float s0 = 0.f, s1 = 0.f, s2 = 0.f, s3 = 0.f;
    #pragma unroll
    for (int i = 0; i < 16; i++) {
      float2 uj = U2[j][i], uk = U2[k][i];
      float p = uj.x * uk.x + uj.y * uk.y;
      s0 += (i & 8) ? -p : p;
      s1 += (i & 4) ? -p : p;
      s2 += (i & 2) ? -p : p;
      s3 += (i & 1) ? -p : p;
    }
    A[0][j][k] = s0; A[1][j][k] = s1; A[2][j][k] = s2; A[3][j][k] = s3;
  }
  __syncthreads();

  // Basis per 2x2 block: f=0: .5(x00+x11)  f=1: .5(x00-x11)  f=2: .5(x01+x10)
  {  // Phase 3a: contract qubit0 (bit3)
    const int w = tid >> 6, j = (tid >> 3) & 7, k = tid & 7;
    float x00 = A[w][j][k],     x01 = A[w][j][k + 8];
    float x10 = A[w][j + 8][k], x11 = A[w][j + 8][k + 8];
    S1[w][0][j][k] = 0.5f * (x00 + x11);
    S1[w][1][j][k] = 0.5f * (x00 - x11);
    S1[w][2][j][k] = 0.5f * (x01 + x10);
  }
  __syncthreads();
  if (tid < 192) {  // Phase 3b: + qubit1
    const int w = tid / 48, r = tid % 48;
    const int f0 = r >> 4, j = (r >> 2) & 3, k = r & 3;
    float x00 = S1[w][f0][j][k],     x01 = S1[w][f0][j][k + 4];
    float x10 = S1[w][f0][j + 4][k], x11 = S1[w][f0][j + 4][k + 4];
    S2[w][f0][0][j][k] = 0.5f * (x00 + x11);
    S2[w][f0][1][j][k] = 0.5f * (x00 - x11);
    S2[w][f0][2][j][k] = 0.5f * (x01 + x10);
  }
  __syncthreads();
  if (tid < 144) {  // Phase 3c: + qubit2
    const int w = tid / 36, r = tid % 36;
    const int f0 = r / 12, f1 = (r >> 2) % 3, j = (r >> 1) & 1, k = r & 1;
    float x00 = S2[w][f0][f1][j][k],     x01 = S2[w][f0][f1][j][k + 2];
    float x10 = S2[w][f0][f1][j + 2][k], x11 = S2[w][f0][f1][j + 2][k + 2];
    S3[w][f0][f1][0][j][k] = 0.5f * (x00 + x11);
    S3[w][f0][f1][1][j][k] = 0.5f * (x00 - x11);
    S3[w][f0][f1][2][j][k] = 0.5f * (x01 + x10);
  }
  __syncthreads();
  if (tid < 108) {  // Phase 3d: + qubit3 -> float4 per (w,f0,f1,f2)
    const int w = tid / 27, r = tid % 27;
    const int f0 = r / 9, f1 = (r / 3) % 3, f2 = r % 3;
    float y00 = S3[w][f0][f1][f2][0][0], y01 = S3[w][f0][f1][f2][0][1];
    float y10 = S3[w][f0][f1][f2][1][0], y11 = S3[w][f0][f1][f2][1][1];
    float4 o;
    o.x = 0.5f * (y00 + y11);
    o.y = 0.5f * (y00 - y11);
    o.z = 0.5f * (y01 + y10);
    o.w = 0.f;
    Cs[tid] = o;
  }

  // ---- Per-sample trig (all threads, before the final barrier) -----------
  ALL8(DECL_TRIG)
  SAMPLE_TRIG(0) SAMPLE_TRIG(1) SAMPLE_TRIG(2) SAMPLE_TRIG(3)
  SAMPLE_TRIG(4) SAMPLE_TRIG(5) SAMPLE_TRIG(6) SAMPLE_TRIG(7)

  __syncthreads();

  // ---- Rolled polynomial contraction (8 samples/thread) ------------------
  #pragma unroll 1
  for (int W = 0; W < 4; W++) {
    float a1_0 = 0.f, a1_1 = 0.f, a1_2 = 0.f, a1_3 = 0.f;
    float a1_4 = 0.f, a1_5 = 0.f, a1_6 = 0.f, a1_7 = 0.f;
    #pragma unroll 1
    for (int e1 = 0; e1 < 3; e1++) {
      const float4* cb = &Cs[W * 27 + e1 * 9];   // runtime base, imm offsets
      float a2_0, a2_1, a2_2, a2_3, a2_4, a2_5, a2_6, a2_7;
      #pragma unroll
      for (int e2 = 0; e2 < 3; e2++) {
        float a3_0, a3_1, a3_2, a3_3, a3_4, a3_5, a3_6, a3_7;
        #pragma unroll
        for (int e3 = 0; e3 < 3; e3++) {
          float4 c = cb[e2 * 3 + e3];
          ALL8(ACC3)
        }
        ALL8(ACC2)
      }
      ALL8(ACC1R)
    }
    Olds[W][0][tid] = a1_0;
    Olds[W][1][tid] = a1_1;
    Olds[W][2][tid] = a1_2;
    Olds[W][3][tid] = a1_3;
    Olds[W][4][tid] = a1_4;
    Olds[W][5][tid] = a1_5;
    Olds[W][6][tid] = a1_6;
    Olds[W][7][tid] = a1_7;
  }

  // Same-thread LDS slots: no barrier needed (compiler inserts lgkmcnt).
  if (act) {
    #pragma unroll
    for (int k = 0; k < 8; k++) {
      out4[gid + k * eighth] = make_float4(Olds[0][k][tid], Olds[1][k][tid],
                                           Olds[2][k][tid], Olds[3][k][tid]);
    }
  }
}

// ---------------------------------------------------------------------------

extern "C" void kernel_launch(void* const* d_in, const int* in_sizes, int n_in,
                              void* d_out, int out_size, void* d_ws, size_t ws_size,
                              hipStream_t stream) {
  const float* x      = (const float*)d_in[0];   // [B,4] f32
  const float* params = (const float*)d_in[1];   // [2,4,3] f32
  float* out = (float*)d_out;                    // [B,4] f32

  int B = in_sizes[0] / 4;
  int eighth = B / 8;
  int blocks = (eighth + 255) / 256;

  qel_fused<<<blocks, 256, 0, stream>>>((const float4*)x, params,
                                        (float4*)out, eighth);
}

// Round 17
// 20.589 us; speedup vs baseline: 8.9816x; 1.0000x over previous
//
#include <hip/hip_runtime.h>

// ---------------------------------------------------------------------------
// QuantumEntanglementLayer: 4 qubits, DIM=16, BATCH=2^20.
// out[b][w] = s^T A_w s,  A_w = Re(U^H Z_w U),  s = tensor prod of RY(|0>).
// Reduced to 4 multilinear polynomials with 81 coeffs each in (1,u_w,v_w),
// u_w = cos(tanh(x_w)*pi/2), v_w = sin(tanh(x_w)*pi/2).
//
// History: rolled W/e1 contract (r14) -> fused (r15) -> 8 samples (r16):
// 34.8 -> 23.0 -> 21.5 -> 20.6. LDS broadcast proved cheap (-0.9 for halved
// traffic); remaining attackable term is contract VALU ISSUE (~2592 FMA/thr).
// This revision: pack the 8 samples into 4 float2 vectors and use
// __builtin_elementwise_fma -> v_pk_fma_f32 (2 FMA/instr, same issue) to
// halve contract issue count. Trig stays scalar (trans ops are scalar).
// ---------------------------------------------------------------------------

typedef __attribute__((ext_vector_type(2))) float v2f;

__device__ __forceinline__ float hwsin(float rad) {
  return __builtin_amdgcn_sinf(rad * 0.15915494309189535f);  // rad -> rev
}
__device__ __forceinline__ float hwcos(float rad) {
  return __builtin_amdgcn_cosf(rad * 0.15915494309189535f);
}

#define TRIGM(xv, U, V) { \
  float e_  = __builtin_amdgcn_exp2f((xv) * 2.8853900817779268f); \
  float th_ = 1.0f - 2.0f * __builtin_amdgcn_rcpf(e_ + 1.0f); \
  U = __builtin_amdgcn_cosf(th_ * 0.25f); \
  V = __builtin_amdgcn_sinf(th_ * 0.25f); }

// One sample-PAIR: X for samples a (->.x) and b (->.y) of pair P.
#define SAMPLE_TRIG_PAIR(P, XA, XB) \
  TRIGM(XA.x, u0_##P.x, v0_##P.x) TRIGM(XA.y, u1_##P.x, v1_##P.x) \
  TRIGM(XA.z, u2_##P.x, v2_##P.x) TRIGM(XA.w, u3_##P.x, v3_##P.x) \
  TRIGM(XB.x, u0_##P.y, v0_##P.y) TRIGM(XB.y, u1_##P.y, v1_##P.y) \
  TRIGM(XB.z, u2_##P.y, v2_##P.y) TRIGM(XB.w, u3_##P.y, v3_##P.y)

#define DECL_TRIG_PAIR(P) \
  v2f u0_##P, v0_##P, u1_##P, v1_##P, u2_##P, v2_##P, u3_##P, v3_##P;

// Packed accumulate: each op is one v_pk_fma_f32 over a sample pair.
#define ACC3P(P) { \
  v2f t_ = __builtin_elementwise_fma(cz2, v3_##P, \
           __builtin_elementwise_fma(cy2, u3_##P, cx2)); \
  if (e3 == 0) a3_##P = t_; \
  else a3_##P = __builtin_elementwise_fma(t_, (e3 == 1) ? u2_##P : v2_##P, a3_##P); }

#define ACC2P(P) { \
  if (e2 == 0) a2_##P = a3_##P; \
  else a2_##P = __builtin_elementwise_fma(a3_##P, (e2 == 1) ? u1_##P : v1_##P, a2_##P); }

// e1 is a RUNTIME loop index: select via cndmask, guard via select.
#define ACC1RP(P) { \
  v2f m_ = (e1 == 1) ? u0_##P : v0_##P; \
  a1_##P = (e1 == 0) ? a2_##P : __builtin_elementwise_fma(a2_##P, m_, a1_##P); }

#define ALLP(M) M(01) M(23) M(45) M(67)

__global__ __launch_bounds__(256) void qel_fused(const float4* __restrict__ x4,
                                                 const float* __restrict__ params,
                                                 float4* __restrict__ out4,
                                                 int eighth) {
  __shared__ float2 U2[16][17];            // circuit state [col][row], +1 pad
  __shared__ float A[4][16][16];           // A_w
  __shared__ float S1[4][3][8][8];         // after contracting qubit0 (f0)
  __shared__ float S2[4][3][3][4][4];      // + qubit1 (f1)
  __shared__ float S3[4][3][3][3][2][2];   // + qubit2 (f2)
  __shared__ float4 Cs[108];               // final coefficients
  __shared__ float Olds[4][8][256];        // [wire][sample][tid] out slots

  const int tid = threadIdx.x;
  const int gid = blockIdx.x * 256 + tid;
  const bool act = gid < eighth;
  const int g = act ? gid : 0;

  // Sample loads first: HBM latency hides under the circuit phases.
  float4 X0 = x4[g];
  float4 X1 = x4[g + eighth];
  float4 X2 = x4[g + 2 * eighth];
  float4 X3 = x4[g + 3 * eighth];
  float4 X4 = x4[g + 4 * eighth];
  float4 X5 = x4[g + 5 * eighth];
  float4 X6 = x4[g + 6 * eighth];
  float4 X7 = x4[g + 7 * eighth];

  // ---- Setup phase 1 (LDS-parallel): U = circuit, one element/thread -----
  {
    const int c = tid >> 4, r = tid & 15;
    U2[c][r] = make_float2((r == c) ? 1.f : 0.f, 0.f);
    __syncthreads();

    #pragma unroll
    for (int layer = 0; layer < 2; layer++) {
      #pragma unroll
      for (int i = 0; i < 3; i++) {        // CNOT(i,i+1): cm=8>>i, tm=4>>i
        const int cm = 8 >> i, tm = 4 >> i;
        const int pr = (r & cm) ? (r ^ tm) : r;
        float2 v = U2[c][pr];
        __syncthreads();
        U2[c][r] = v;
        __syncthreads();
      }
      #pragma unroll
      for (int w = 0; w < 4; w++) {        // Rot(phi,theta,omega) on wire w
        float phi   = params[layer * 12 + w * 3 + 0];
        float theta = params[layer * 12 + w * 3 + 1];
        float omega = params[layer * 12 + w * 3 + 2];
        float ct = hwcos(theta * 0.5f), st = hwsin(theta * 0.5f);
        float ap = -0.5f * (phi + omega), am = 0.5f * (phi - omega);
        float g00r =  hwcos(ap) * ct, g00i =  hwsin(ap) * ct;
        float g01r = -hwcos(am) * st, g01i = -hwsin(am) * st;
        float g10r =  hwcos(am) * st, g10i = -hwsin(am) * st;
        float g11r =  g00r,           g11i = -g00i;
        const int tm = 8 >> w;
        const int r0 = r & ~tm, r1 = r | tm;
        const bool hi = (r & tm) != 0;
        float gar = hi ? g10r : g00r, gai = hi ? g10i : g00i;
        float gbr = hi ? g11r : g01r, gbi = hi ? g11i : g01i;
        float2 o0 = U2[c][r0], o1 = U2[c][r1];
        __syncthreads();
        float nr = gar * o0.x - gai * o0.y + gbr * o1.x - gbi * o1.y;
        float ni = gar * o0.y + gai * o0.x + gbr * o1.y + gbi * o1.x;
        U2[c][r] = make_float2(nr, ni);
        __syncthreads();
      }
      {                                    // CNOT(0,3): cm=8, tm=1
        const int pr = (r & 8) ? (r ^ 1) : r;
        float2 v = U2[c][pr];
        __syncthreads();
        U2[c][r] = v;
        __syncthreads();
      }
    }
  }

  // ---- Setup phase 2: A_w[j][k] = sum_i z_w[i] Re(conj(U_ij) U_ik) -------
  {
    const int j = tid >> 4, k = tid & 15;
    float s0 = 0.f, s1 = 0.f, s2 = 0.f, s3 = 0.f;
    #pragma unroll
    for (int i = 0; i < 16; i++) {
      float2 uj = U2[j][i], uk = U2[k][i];
      float p = uj.x * uk.x + uj.y * uk.y;
      s0 += (i & 8) ? -p : p;
      s1 += (i & 4) ? -p : p;
      s2 += (i & 2) ? -p : p;
      s3 += (i & 1) ? -p : p;
    }
    A[0][j][k] = s0; A[1][j][k] = s1; A[2][j][k] = s2; A[3][j][k] = s3;
  }
  __syncthreads();

  // Basis per 2x2 block: f=0: .5(x00+x11)  f=1: .5(x00-x11)  f=2: .5(x01+x10)
  {  // Phase 3a: contract qubit0 (bit3)
    const int w = tid >> 6, j = (tid >> 3) & 7, k = tid & 7;
    float x00 = A[w][j][k],     x01 = A[w][j][k + 8];
    float x10 = A[w][j + 8][k], x11 = A[w][j + 8][k + 8];
    S1[w][0][j][k] = 0.5f * (x00 + x11);
    S1[w][1][j][k] = 0.5f * (x00 - x11);
    S1[w][2][j][k] = 0.5f * (x01 + x10);
  }
  __syncthreads();
  if (tid < 192) {  // Phase 3b: + qubit1
    const int w = tid / 48, r = tid % 48;
    const int f0 = r >> 4, j = (r >> 2) & 3, k = r & 3;
    float x00 = S1[w][f0][j][k],     x01 = S1[w][f0][j][k + 4];
    float x10 = S1[w][f0][j + 4][k], x11 = S1[w][f0][j + 4][k + 4];
    S2[w][f0][0][j][k] = 0.5f * (x00 + x11);
    S2[w][f0][1][j][k] = 0.5f * (x00 - x11);
    S2[w][f0][2][j][k] = 0.5f * (x01 + x10);
  }
  __syncthreads();
  if (tid < 144) {  // Phase 3c: + qubit2
    const int w = tid / 36, r = tid % 36;
    const int f0 = r / 12, f1 = (r >> 2) % 3, j = (r >> 1) & 1, k = r & 1;
    float x00 = S2[w][f0][f1][j][k],     x01 = S2[w][f0][f1][j][k + 2];
    float x10 = S2[w][f0][f1][j + 2][k], x11 = S2[w][f0][f1][j + 2][k + 2];
    S3[w][f0][f1][0][j][k] = 0.5f * (x00 + x11);
    S3[w][f0][f1][1][j][k] = 0.5f * (x00 - x11);
    S3[w][f0][f1][2][j][k] = 0.5f * (x01 + x10);
  }
  __syncthreads();
  if (tid < 108) {  // Phase 3d: + qubit3 -> float4 per (w,f0,f1,f2)
    const int w = tid / 27, r = tid % 27;
    const int f0 = r / 9, f1 = (r / 3) % 3, f2 = r % 3;
    float y00 = S3[w][f0][f1][f2][0][0], y01 = S3[w][f0][f1][f2][0][1];
    float y10 = S3[w][f0][f1][f2][1][0], y11 = S3[w][f0][f1][f2][1][1];
    float4 o;
    o.x = 0.5f * (y00 + y11);
    o.y = 0.5f * (y00 - y11);
    o.z = 0.5f * (y01 + y10);
    o.w = 0.f;
    Cs[tid] = o;
  }

  // ---- Per-sample trig (scalar trans ops, packed into pairs) -------------
  ALLP(DECL_TRIG_PAIR)
  SAMPLE_TRIG_PAIR(01, X0, X1)
  SAMPLE_TRIG_PAIR(23, X2, X3)
  SAMPLE_TRIG_PAIR(45, X4, X5)
  SAMPLE_TRIG_PAIR(67, X6, X7)

  __syncthreads();

  // ---- Rolled packed contraction (4 float2 pairs = 8 samples) ------------
  #pragma unroll 1
  for (int W = 0; W < 4; W++) {
    v2f a1_01 = {0.f, 0.f}, a1_23 = {0.f, 0.f};
    v2f a1_45 = {0.f, 0.f}, a1_67 = {0.f, 0.f};
    #pragma unroll 1
    for (int e1 = 0; e1 < 3; e1++) {
      const float4* cb = &Cs[W * 27 + e1 * 9];   // runtime base, imm offsets
      v2f a2_01, a2_23, a2_45, a2_67;
      #pragma unroll
      for (int e2 = 0; e2 < 3; e2++) {
        v2f a3_01, a3_23, a3_45, a3_67;
        #pragma unroll
        for (int e3 = 0; e3 < 3; e3++) {
          float4 c = cb[e2 * 3 + e3];
          v2f cx2 = {c.x, c.x}, cy2 = {c.y, c.y}, cz2 = {c.z, c.z};
          ALLP(ACC3P)
        }
        ALLP(ACC2P)
      }
      ALLP(ACC1RP)
    }
    Olds[W][0][tid] = a1_01.x;
    Olds[W][1][tid] = a1_01.y;
    Olds[W][2][tid] = a1_23.x;
    Olds[W][3][tid] = a1_23.y;
    Olds[W][4][tid] = a1_45.x;
    Olds[W][5][tid] = a1_45.y;
    Olds[W][6][tid] = a1_67.x;
    Olds[W][7][tid] = a1_67.y;
  }

  // Same-thread LDS slots: no barrier needed (compiler inserts lgkmcnt).
  if (act) {
    #pragma unroll
    for (int k = 0; k < 8; k++) {
      out4[gid + k * eighth] = make_float4(Olds[0][k][tid], Olds[1][k][tid],
                                           Olds[2][k][tid], Olds[3][k][tid]);
    }
  }
}

// ---------------------------------------------------------------------------

extern "C" void kernel_launch(void* const* d_in, const int* in_sizes, int n_in,
                              void* d_out, int out_size, void* d_ws, size_t ws_size,
                              hipStream_t stream) {
  const float* x      = (const float*)d_in[0];   // [B,4] f32
  const float* params = (const float*)d_in[1];   // [2,4,3] f32
  float* out = (float*)d_out;                    // [B,4] f32

  int B = in_sizes[0] / 4;
  int eighth = B / 8;
  int blocks = (eighth + 255) / 256;

  qel_fused<<<blocks, 256, 0, stream>>>((const float4*)x, params,
                                        (float4*)out, eighth);
}

// Round 18
// 19.570 us; speedup vs baseline: 9.4494x; 1.0521x over previous
//
#include <hip/hip_runtime.h>

// ---------------------------------------------------------------------------
// QuantumEntanglementLayer: 4 qubits, DIM=16, BATCH=2^20.
// out[b][w] = s^T A_w s,  A_w = Re(U^H Z_w U),  s = tensor prod of RY(|0>).
// Reduced to 4 multilinear polynomials with 81 coeffs each in (1,u_w,v_w),
// u_w = cos(tanh(x_w)*pi/2), v_w = sin(tanh(x_w)*pi/2).
//
// History: 39.0 -> 34.8 (LDS coeffs + parallel setup) -> 23.0 (rolled
// contract: killed the 240-VGPR balloon) -> 21.5 (fused) -> 20.6 (8 samp).
// r17 packed-math: exact null -> contract issue is NOT the binding term.
// This revision attacks the per-block setup serial chain: phase 1's 16
// gate steps x 2 barriers (~37 barriers, LDS-RAW latency each) become a
// BARRIER-FREE __shfl_xor chain -- U's columns evolve independently and
// each 16-lane column group lives inside one wave, so row partner r^tm
// (tm<16) is one shuffle away. One barrier total before phase 2.
// ---------------------------------------------------------------------------

typedef __attribute__((ext_vector_type(2))) float v2f;

__device__ __forceinline__ float hwsin(float rad) {
  return __builtin_amdgcn_sinf(rad * 0.15915494309189535f);  // rad -> rev
}
__device__ __forceinline__ float hwcos(float rad) {
  return __builtin_amdgcn_cosf(rad * 0.15915494309189535f);
}

#define TRIGM(xv, U, V) { \
  float e_  = __builtin_amdgcn_exp2f((xv) * 2.8853900817779268f); \
  float th_ = 1.0f - 2.0f * __builtin_amdgcn_rcpf(e_ + 1.0f); \
  U = __builtin_amdgcn_cosf(th_ * 0.25f); \
  V = __builtin_amdgcn_sinf(th_ * 0.25f); }

// One sample-PAIR: X for samples a (->.x) and b (->.y) of pair P.
#define SAMPLE_TRIG_PAIR(P, XA, XB) \
  TRIGM(XA.x, u0_##P.x, v0_##P.x) TRIGM(XA.y, u1_##P.x, v1_##P.x) \
  TRIGM(XA.z, u2_##P.x, v2_##P.x) TRIGM(XA.w, u3_##P.x, v3_##P.x) \
  TRIGM(XB.x, u0_##P.y, v0_##P.y) TRIGM(XB.y, u1_##P.y, v1_##P.y) \
  TRIGM(XB.z, u2_##P.y, v2_##P.y) TRIGM(XB.w, u3_##P.y, v3_##P.y)

#define DECL_TRIG_PAIR(P) \
  v2f u0_##P, v0_##P, u1_##P, v1_##P, u2_##P, v2_##P, u3_##P, v3_##P;

// Packed accumulate: each op is one v_pk_fma_f32 over a sample pair.
#define ACC3P(P) { \
  v2f t_ = __builtin_elementwise_fma(cz2, v3_##P, \
           __builtin_elementwise_fma(cy2, u3_##P, cx2)); \
  if (e3 == 0) a3_##P = t_; \
  else a3_##P = __builtin_elementwise_fma(t_, (e3 == 1) ? u2_##P : v2_##P, a3_##P); }

#define ACC2P(P) { \
  if (e2 == 0) a2_##P = a3_##P; \
  else a2_##P = __builtin_elementwise_fma(a3_##P, (e2 == 1) ? u1_##P : v1_##P, a2_##P); }

// e1 is a RUNTIME loop index: select via cndmask, guard via select.
#define ACC1RP(P) { \
  v2f m_ = (e1 == 1) ? u0_##P : v0_##P; \
  a1_##P = (e1 == 0) ? a2_##P : __builtin_elementwise_fma(a2_##P, m_, a1_##P); }

#define ALLP(M) M(01) M(23) M(45) M(67)

__global__ __launch_bounds__(256) void qel_fused(const float4* __restrict__ x4,
                                                 const float* __restrict__ params,
                                                 float4* __restrict__ out4,
                                                 int eighth) {
  __shared__ float2 U2[16][17];            // final U [col][row], +1 pad
  __shared__ float A[4][16][16];           // A_w
  __shared__ float S1[4][3][8][8];         // after contracting qubit0 (f0)
  __shared__ float S2[4][3][3][4][4];      // + qubit1 (f1)
  __shared__ float S3[4][3][3][3][2][2];   // + qubit2 (f2)
  __shared__ float4 Cs[108];               // final coefficients
  __shared__ float Olds[4][8][256];        // [wire][sample][tid] out slots

  const int tid = threadIdx.x;
  const int gid = blockIdx.x * 256 + tid;
  const bool act = gid < eighth;
  const int g = act ? gid : 0;

  // Sample loads first: HBM latency hides under the circuit phases.
  float4 X0 = x4[g];
  float4 X1 = x4[g + eighth];
  float4 X2 = x4[g + 2 * eighth];
  float4 X3 = x4[g + 3 * eighth];
  float4 X4 = x4[g + 4 * eighth];
  float4 X5 = x4[g + 5 * eighth];
  float4 X6 = x4[g + 6 * eighth];
  float4 X7 = x4[g + 7 * eighth];

  // ---- Setup phase 1 (shuffle-parallel, BARRIER-FREE): ------------------
  // Thread (c, r) carries U[r][c] in registers. Columns evolve
  // independently; row partner r^tm (tm in {1,2,4,8} < 16) is in the same
  // 16-lane group of the same wave -> __shfl_xor. Zero barriers, zero LDS.
  {
    const int c = tid >> 4, r = tid & 15;
    float vr = (r == c) ? 1.f : 0.f;
    float vi = 0.f;

    #pragma unroll
    for (int layer = 0; layer < 2; layer++) {
      #pragma unroll
      for (int i = 0; i < 3; i++) {        // CNOT(i,i+1): cm=8>>i, tm=4>>i
        const int cm = 8 >> i, tm = 4 >> i;
        float pvr = __shfl_xor(vr, tm);
        float pvi = __shfl_xor(vi, tm);
        vr = (r & cm) ? pvr : vr;
        vi = (r & cm) ? pvi : vi;
      }
      #pragma unroll
      for (int w = 0; w < 4; w++) {        // Rot(phi,theta,omega) on wire w
        float phi   = params[layer * 12 + w * 3 + 0];
        float theta = params[layer * 12 + w * 3 + 1];
        float omega = params[layer * 12 + w * 3 + 2];
        float ct = hwcos(theta * 0.5f), st = hwsin(theta * 0.5f);
        float ap = -0.5f * (phi + omega), am = 0.5f * (phi - omega);
        float g00r =  hwcos(ap) * ct, g00i =  hwsin(ap) * ct;
        float g01r = -hwcos(am) * st, g01i = -hwsin(am) * st;
        float g10r =  hwcos(am) * st, g10i = -hwsin(am) * st;
        float g11r =  g00r,           g11i = -g00i;
        const int tm = 8 >> w;
        const bool hi = (r & tm) != 0;
        float pvr = __shfl_xor(vr, tm);
        float pvi = __shfl_xor(vi, tm);
        float o0r = hi ? pvr : vr, o0i = hi ? pvi : vi;
        float o1r = hi ? vr : pvr, o1i = hi ? vi : pvi;
        float gar = hi ? g10r : g00r, gai = hi ? g10i : g00i;
        float gbr = hi ? g11r : g01r, gbi = hi ? g11i : g01i;
        vr = gar * o0r - gai * o0i + gbr * o1r - gbi * o1i;
        vi = gar * o0i + gai * o0r + gbr * o1i + gbi * o1r;
      }
      {                                    // CNOT(0,3): cm=8, tm=1
        float pvr = __shfl_xor(vr, 1);
        float pvi = __shfl_xor(vi, 1);
        vr = (r & 8) ? pvr : vr;
        vi = (r & 8) ? pvi : vi;
      }
    }
    U2[c][r] = make_float2(vr, vi);
  }
  __syncthreads();

  // ---- Setup phase 2: A_w[j][k] = sum_i z_w[i] Re(conj(U_ij) U_ik) -------
  {
    const int j = tid >> 4, k = tid & 15;
    float s0 = 0.f, s1 = 0.f, s2 = 0.f, s3 = 0.f;
    #pragma unroll
    for (int i = 0; i < 16; i++) {
      float2 uj = U2[j][i], uk = U2[k][i];
      float p = uj.x * uk.x + uj.y * uk.y;
      s0 += (i & 8) ? -p : p;
      s1 += (i & 4) ? -p : p;
      s2 += (i & 2) ? -p : p;
      s3 += (i & 1) ? -p : p;
    }
    A[0][j][k] = s0; A[1][j][k] = s1; A[2][j][k] = s2; A[3][j][k] = s3;
  }
  __syncthreads();

  // Basis per 2x2 block: f=0: .5(x00+x11)  f=1: .5(x00-x11)  f=2: .5(x01+x10)
  {  // Phase 3a: contract qubit0 (bit3)
    const int w = tid >> 6, j = (tid >> 3) & 7, k = tid & 7;
    float x00 = A[w][j][k],     x01 = A[w][j][k + 8];
    float x10 = A[w][j + 8][k], x11 = A[w][j + 8][k + 8];
    S1[w][0][j][k] = 0.5f * (x00 + x11);
    S1[w][1][j][k] = 0.5f * (x00 - x11);
    S1[w][2][j][k] = 0.5f * (x01 + x10);
  }
  __syncthreads();
  if (tid < 192) {  // Phase 3b: + qubit1
    const int w = tid / 48, r = tid % 48;
    const int f0 = r >> 4, j = (r >> 2) & 3, k = r & 3;
    float x00 = S1[w][f0][j][k],     x01 = S1[w][f0][j][k + 4];
    float x10 = S1[w][f0][j + 4][k], x11 = S1[w][f0][j + 4][k + 4];
    S2[w][f0][0][j][k] = 0.5f * (x00 + x11);
    S2[w][f0][1][j][k] = 0.5f * (x00 - x11);
    S2[w][f0][2][j][k] = 0.5f * (x01 + x10);
  }
  __syncthreads();
  if (tid < 144) {  // Phase 3c: + qubit2
    const int w = tid / 36, r = tid % 36;
    const int f0 = r / 12, f1 = (r >> 2) % 3, j = (r >> 1) & 1, k = r & 1;
    float x00 = S2[w][f0][f1][j][k],     x01 = S2[w][f0][f1][j][k + 2];
    float x10 = S2[w][f0][f1][j + 2][k], x11 = S2[w][f0][f1][j + 2][k + 2];
    S3[w][f0][f1][0][j][k] = 0.5f * (x00 + x11);
    S3[w][f0][f1][1][j][k] = 0.5f * (x00 - x11);
    S3[w][f0][f1][2][j][k] = 0.5f * (x01 + x10);
  }
  __syncthreads();
  if (tid < 108) {  // Phase 3d: + qubit3 -> float4 per (w,f0,f1,f2)
    const int w = tid / 27, r = tid % 27;
    const int f0 = r / 9, f1 = (r / 3) % 3, f2 = r % 3;
    float y00 = S3[w][f0][f1][f2][0][0], y01 = S3[w][f0][f1][f2][0][1];
    float y10 = S3[w][f0][f1][f2][1][0], y11 = S3[w][f0][f1][f2][1][1];
    float4 o;
    o.x = 0.5f * (y00 + y11);
    o.y = 0.5f * (y00 - y11);
    o.z = 0.5f * (y01 + y10);
    o.w = 0.f;
    Cs[tid] = o;
  }

  // ---- Per-sample trig (scalar trans ops, packed into pairs) -------------
  ALLP(DECL_TRIG_PAIR)
  SAMPLE_TRIG_PAIR(01, X0, X1)
  SAMPLE_TRIG_PAIR(23, X2, X3)
  SAMPLE_TRIG_PAIR(45, X4, X5)
  SAMPLE_TRIG_PAIR(67, X6, X7)

  __syncthreads();

  // ---- Rolled packed contraction (4 float2 pairs = 8 samples) ------------
  #pragma unroll 1
  for (int W = 0; W < 4; W++) {
    v2f a1_01 = {0.f, 0.f}, a1_23 = {0.f, 0.f};
    v2f a1_45 = {0.f, 0.f}, a1_67 = {0.f, 0.f};
    #pragma unroll 1
    for (int e1 = 0; e1 < 3; e1++) {
      const float4* cb = &Cs[W * 27 + e1 * 9];   // runtime base, imm offsets
      v2f a2_01, a2_23, a2_45, a2_67;
      #pragma unroll
      for (int e2 = 0; e2 < 3; e2++) {
        v2f a3_01, a3_23, a3_45, a3_67;
        #pragma unroll
        for (int e3 = 0; e3 < 3; e3++) {
          float4 c = cb[e2 * 3 + e3];
          v2f cx2 = {c.x, c.x}, cy2 = {c.y, c.y}, cz2 = {c.z, c.z};
          ALLP(ACC3P)
        }
        ALLP(ACC2P)
      }
      ALLP(ACC1RP)
    }
    Olds[W][0][tid] = a1_01.x;
    Olds[W][1][tid] = a1_01.y;
    Olds[W][2][tid] = a1_23.x;
    Olds[W][3][tid] = a1_23.y;
    Olds[W][4][tid] = a1_45.x;
    Olds[W][5][tid] = a1_45.y;
    Olds[W][6][tid] = a1_67.x;
    Olds[W][7][tid] = a1_67.y;
  }

  // Same-thread LDS slots: no barrier needed (compiler inserts lgkmcnt).
  if (act) {
    #pragma unroll
    for (int k = 0; k < 8; k++) {
      out4[gid + k * eighth] = make_float4(Olds[0][k][tid], Olds[1][k][tid],
                                           Olds[2][k][tid], Olds[3][k][tid]);
    }
  }
}

// ---------------------------------------------------------------------------

extern "C" void kernel_launch(void* const* d_in, const int* in_sizes, int n_in,
                              void* d_out, int out_size, void* d_ws, size_t ws_size,
                              hipStream_t stream) {
  const float* x      = (const float*)d_in[0];   // [B,4] f32
  const float* params = (const float*)d_in[1];   // [2,4,3] f32
  float* out = (float*)d_out;                    // [B,4] f32

  int B = in_sizes[0] / 4;
  int eighth = B / 8;
  int blocks = (eighth + 255) / 256;

  qel_fused<<<blocks, 256, 0, stream>>>((const float4*)x, params,
                                        (float4*)out, eighth);
}